// Round 5
// baseline (643.430 us; speedup 1.0000x reference)
//
#include <hip/hip_runtime.h>
#include <math.h>

#define NEG_SLOPE 0.2f

typedef __attribute__((ext_vector_type(8))) short bf16x8;
typedef __attribute__((ext_vector_type(4))) float f32x4;
typedef unsigned short u16;
typedef __attribute__((ext_vector_type(4))) unsigned short u16x4;

__device__ __forceinline__ float b2f(u16 u) {
    return __uint_as_float(((unsigned)u) << 16);
}
__device__ __forceinline__ u16 f2b(float f) {
    unsigned u = __float_as_uint(f);
    unsigned r = (u + 0x7fffu + ((u >> 16) & 1u)) >> 16;
    return (u16)r;
}

// ---------------- casts / transposes ----------------
__global__ void cast_f2b4(const float* __restrict__ in, u16* __restrict__ out, int n4) {
    int i = blockIdx.x * blockDim.x + threadIdx.x;
    if (i < n4) {
        float4 v = *reinterpret_cast<const float4*>(&in[i * 4]);
        u16x4 o;
        o[0] = f2b(v.x); o[1] = f2b(v.y); o[2] = f2b(v.z); o[3] = f2b(v.w);
        *reinterpret_cast<u16x4*>(&out[i * 4]) = o;
    }
}

// W[K][M] fp32 -> Wt[M][K] bf16
__global__ void transpose_w(const float* __restrict__ W, u16* __restrict__ Wt,
                            int K, int M) {
    int i = blockIdx.x * blockDim.x + threadIdx.x;
    if (i < K * M) {
        int m = i / K, k = i - m * K;
        Wt[i] = f2b(W[(size_t)k * M + m]);
    }
}

// ---------------- MFMA GEMM: C[N,M] bf16 = A[N,K] bf16 * Bt[M,K]^T ----------
__global__ __launch_bounds__(256) void gemm_mfma(
        const u16* __restrict__ A, const u16* __restrict__ Bt,
        u16* __restrict__ C, int N, int K, int M) {
    __shared__ u16 As[128 * 64];
    __shared__ u16 Bs[128 * 64];
    const int tid = threadIdx.x;
    const int lane = tid & 63;
    const int wid = tid >> 6;
    const int wr = wid >> 1, wc = wid & 1;
    const int row0 = blockIdx.x * 128;
    const int col0 = blockIdx.y * 128;
    f32x4 acc[4][4] = {};
    for (int k0 = 0; k0 < K; k0 += 64) {
        if (k0) __syncthreads();
#pragma unroll
        for (int i = 0; i < 4; ++i) {
            int chunk = i * 256 + tid;
            int row = chunk >> 3;
            int slot = chunk & 7;
            int grow = row0 + row; if (grow >= N) grow = N - 1;
            bf16x8 v = *reinterpret_cast<const bf16x8*>(&A[(size_t)grow * K + k0 + slot * 8]);
            int swz = (chunk & ~7) | (slot ^ (row & 7));
            *reinterpret_cast<bf16x8*>(&As[swz * 8]) = v;
        }
#pragma unroll
        for (int i = 0; i < 4; ++i) {
            int chunk = i * 256 + tid;
            int row = chunk >> 3;
            int slot = chunk & 7;
            int gcol = col0 + row;
            bf16x8 v = *reinterpret_cast<const bf16x8*>(&Bt[(size_t)gcol * K + k0 + slot * 8]);
            int swz = (chunk & ~7) | (slot ^ (row & 7));
            *reinterpret_cast<bf16x8*>(&Bs[swz * 8]) = v;
        }
        __syncthreads();
#pragma unroll
        for (int kk = 0; kk < 2; ++kk) {
            bf16x8 ax[4], bx[4];
#pragma unroll
            for (int m = 0; m < 4; ++m) {
                int row = wr * 64 + m * 16 + (lane & 15);
                int slot = kk * 4 + (lane >> 4);
                ax[m] = *reinterpret_cast<const bf16x8*>(&As[(row * 8 + (slot ^ (row & 7))) * 8]);
            }
#pragma unroll
            for (int n = 0; n < 4; ++n) {
                int row = wc * 64 + n * 16 + (lane & 15);
                int slot = kk * 4 + (lane >> 4);
                bx[n] = *reinterpret_cast<const bf16x8*>(&Bs[(row * 8 + (slot ^ (row & 7))) * 8]);
            }
#pragma unroll
            for (int m = 0; m < 4; ++m)
#pragma unroll
                for (int n = 0; n < 4; ++n)
                    acc[m][n] = __builtin_amdgcn_mfma_f32_16x16x32_bf16(
                        ax[m], bx[n], acc[m][n], 0, 0, 0);
        }
    }
    const int crow = row0 + wr * 64;
    const int ccol = col0 + wc * 64;
#pragma unroll
    for (int m = 0; m < 4; ++m)
#pragma unroll
        for (int n = 0; n < 4; ++n)
#pragma unroll
            for (int r = 0; r < 4; ++r) {
                int rg = crow + m * 16 + (lane >> 4) * 4 + r;
                int cg = ccol + n * 16 + (lane & 15);
                if (rg < N) C[(size_t)rg * M + cg] = f2b(acc[m][n][r]);
            }
}

// ---------------- per-node attention dots (bf16 h, H=4, C=64) --------------
__global__ void compute_al_b(const u16* __restrict__ h, const float* __restrict__ a_s,
                             const float* __restrict__ a_d, int N,
                             float* __restrict__ al_s, float* __restrict__ al_d) {
    int i = blockIdx.x * blockDim.x + threadIdx.x;   // n*4 + head
    if (i < N * 4) {
        int hh = i & 3;
        const u16* hp = h + (size_t)(i >> 2) * 256 + hh * 64;
        const float* as = a_s + hh * 64;
        const float* ad = a_d + hh * 64;
        float ss = 0.f, sd = 0.f;
        for (int c0 = 0; c0 < 64; c0 += 8) {
            bf16x8 v = *reinterpret_cast<const bf16x8*>(&hp[c0]);
#pragma unroll
            for (int j = 0; j < 8; ++j) {
                float f = b2f((u16)v[j]);
                ss = fmaf(f, as[c0 + j], ss);
                sd = fmaf(f, ad[c0 + j], sd);
            }
        }
        al_s[i] = ss; al_d[i] = sd;
    }
}

// ---------------- CSR build ----------------
__global__ void deg_hist(const int* __restrict__ dstI, int E, int Etot,
                         int* __restrict__ cnt) {
    int e = blockIdx.x * blockDim.x + threadIdx.x;
    if (e < Etot) {
        int d = (e < E) ? dstI[e] : (e - E);
        atomicAdd(&cnt[d], 1);
    }
}

// single-block exclusive scan, 4 elements/thread (writes rp AND cursor)
__global__ __launch_bounds__(1024) void scan_excl4(const int* __restrict__ cnt,
                                                   int* __restrict__ rp,
                                                   int* __restrict__ cursor, int N) {
    __shared__ int wsum[16];
    __shared__ int carry_s;
    int lane = threadIdx.x & 63;
    int wid = threadIdx.x >> 6;
    if (threadIdx.x == 0) carry_s = 0;
    __syncthreads();
    for (int base = 0; base < N; base += 4096) {
        int idx = base + (int)threadIdx.x * 4;
        int a0 = 0, a1 = 0, a2 = 0, a3 = 0;
        if (idx + 3 < N) {
            int4 v = *reinterpret_cast<const int4*>(&cnt[idx]);
            a0 = v.x; a1 = v.y; a2 = v.z; a3 = v.w;
        } else {
            if (idx < N)     a0 = cnt[idx];
            if (idx + 1 < N) a1 = cnt[idx + 1];
            if (idx + 2 < N) a2 = cnt[idx + 2];
        }
        int p1 = a0 + a1, p2 = p1 + a2, p3 = p2 + a3;
        int x = p3;
#pragma unroll
        for (int ofs = 1; ofs < 64; ofs <<= 1) {
            int t = __shfl_up(x, ofs, 64);
            if (lane >= ofs) x += t;
        }
        if (lane == 63) wsum[wid] = x;
        __syncthreads();
        if (wid == 0) {
            int y = (lane < 16) ? wsum[lane] : 0;
#pragma unroll
            for (int ofs = 1; ofs < 16; ofs <<= 1) {
                int t = __shfl_up(y, ofs, 64);
                if (lane >= ofs) y += t;
            }
            if (lane < 16) wsum[lane] = y;
        }
        __syncthreads();
        int wofs = (wid > 0) ? wsum[wid - 1] : 0;
        int carry = carry_s;
        int excl = carry + wofs + (x - p3);
        if (idx < N)     { rp[idx] = excl;          cursor[idx] = excl; }
        if (idx + 1 < N) { rp[idx + 1] = excl + a0; cursor[idx + 1] = excl + a0; }
        if (idx + 2 < N) { rp[idx + 2] = excl + p1; cursor[idx + 2] = excl + p1; }
        if (idx + 3 < N) { rp[idx + 3] = excl + p2; cursor[idx + 3] = excl + p2; }
        __syncthreads();
        if (threadIdx.x == 1023) carry_s = carry + wsum[15];
        __syncthreads();
    }
    if (threadIdx.x == 0) rp[N] = carry_s;
}

__global__ void csr_scatter(const int* __restrict__ srcI, const int* __restrict__ dstI,
                            int E, int Etot, int* __restrict__ cursor,
                            int* __restrict__ srcp) {
    int e = blockIdx.x * blockDim.x + threadIdx.x;
    if (e < Etot) {
        int s, d;
        if (e < E) { s = srcI[e]; d = dstI[e]; }
        else       { s = e - E;   d = e - E; }
        int pos = atomicAdd(&cursor[d], 1);
        srcp[pos] = s;
    }
}

// ---------------- single-pass fused aggregate, H=4, C=64 --------------------
template<bool ELU>
__global__ __launch_bounds__(256) void gat_fused_h4(
        const u16* __restrict__ h, const float* __restrict__ al_s,
        const float* __restrict__ al_d, const float* __restrict__ b,
        const int* __restrict__ rp, const int* __restrict__ srcp,
        int N, u16* __restrict__ out) {
    const int lane = threadIdx.x & 63;
    const int head = lane >> 4;
    int w = (blockIdx.x * blockDim.x + threadIdx.x) >> 6;
    int nw = (gridDim.x * blockDim.x) >> 6;
    for (int d = w; d < N; d += nw) {
        int i = rp[d], end = rp[d + 1];
        float ald = al_d[d * 4 + head];
        float acc0 = 0.f, acc1 = 0.f, acc2 = 0.f, acc3 = 0.f, L = 0.f;
        for (; i + 2 <= end; i += 2) {
            int s0 = srcp[i], s1 = srcp[i + 1];
            u16x4 h0 = *reinterpret_cast<const u16x4*>(&h[(size_t)s0 * 256 + lane * 4]);
            u16x4 h1 = *reinterpret_cast<const u16x4*>(&h[(size_t)s1 * 256 + lane * 4]);
            float v0 = al_s[s0 * 4 + head] + ald;
            float v1 = al_s[s1 * 4 + head] + ald;
            v0 = (v0 > 0.f) ? v0 : NEG_SLOPE * v0;
            v1 = (v1 > 0.f) ? v1 : NEG_SLOPE * v1;
            float e0 = expf(v0), e1 = expf(v1);
            L += e0 + e1;
            acc0 = fmaf(e0, b2f((u16)h0[0]), acc0);
            acc1 = fmaf(e0, b2f((u16)h0[1]), acc1);
            acc2 = fmaf(e0, b2f((u16)h0[2]), acc2);
            acc3 = fmaf(e0, b2f((u16)h0[3]), acc3);
            acc0 = fmaf(e1, b2f((u16)h1[0]), acc0);
            acc1 = fmaf(e1, b2f((u16)h1[1]), acc1);
            acc2 = fmaf(e1, b2f((u16)h1[2]), acc2);
            acc3 = fmaf(e1, b2f((u16)h1[3]), acc3);
        }
        if (i < end) {
            int s0 = srcp[i];
            u16x4 h0 = *reinterpret_cast<const u16x4*>(&h[(size_t)s0 * 256 + lane * 4]);
            float v0 = al_s[s0 * 4 + head] + ald;
            v0 = (v0 > 0.f) ? v0 : NEG_SLOPE * v0;
            float e0 = expf(v0);
            L += e0;
            acc0 = fmaf(e0, b2f((u16)h0[0]), acc0);
            acc1 = fmaf(e0, b2f((u16)h0[1]), acc1);
            acc2 = fmaf(e0, b2f((u16)h0[2]), acc2);
            acc3 = fmaf(e0, b2f((u16)h0[3]), acc3);
        }
        float inv = 1.f / (L + 1e-16f);
        float4 bb = *reinterpret_cast<const float4*>(&b[lane * 4]);
        float o0 = fmaf(acc0, inv, bb.x);
        float o1 = fmaf(acc1, inv, bb.y);
        float o2 = fmaf(acc2, inv, bb.z);
        float o3 = fmaf(acc3, inv, bb.w);
        if (ELU) {
            o0 = (o0 > 0.f) ? o0 : expm1f(o0);
            o1 = (o1 > 0.f) ? o1 : expm1f(o1);
            o2 = (o2 > 0.f) ? o2 : expm1f(o2);
            o3 = (o3 > 0.f) ? o3 : expm1f(o3);
        }
        u16x4 ov;
        ov[0] = f2b(o0); ov[1] = f2b(o1); ov[2] = f2b(o2); ov[3] = f2b(o3);
        *reinterpret_cast<u16x4*>(&out[(size_t)d * 256 + lane * 4]) = ov;
    }
}

// ================= layer-3 linear-collapse path =============================
// was[k] = sum_c W3[k][c]*a_src3[c];  wad likewise
__global__ void make_wasd(const float* __restrict__ W3, const float* __restrict__ as3,
                          const float* __restrict__ ad3,
                          float* __restrict__ was, float* __restrict__ wad) {
    int k = threadIdx.x;  // 256
    float ss = 0.f, sd = 0.f;
#pragma unroll
    for (int c = 0; c < 10; ++c) {
        float w = W3[k * 10 + c];
        ss = fmaf(w, as3[c], ss);
        sd = fmaf(w, ad3[c], sd);
    }
    was[k] = ss; wad[k] = sd;
}

// al_s[n] = ob[n,:] . was ;  al_d[n] = ob[n,:] . wad  (one wave per node)
__global__ __launch_bounds__(256) void compute_al3(
        const u16* __restrict__ ob, const float* __restrict__ was,
        const float* __restrict__ wad, int N,
        float* __restrict__ al_s, float* __restrict__ al_d) {
    const int lane = threadIdx.x & 63;
    int n = (blockIdx.x * blockDim.x + threadIdx.x) >> 6;
    if (n >= N) return;
    u16x4 hv = *reinterpret_cast<const u16x4*>(&ob[(size_t)n * 256 + lane * 4]);
    float4 ws = *reinterpret_cast<const float4*>(&was[lane * 4]);
    float4 wd = *reinterpret_cast<const float4*>(&wad[lane * 4]);
    float f0 = b2f((u16)hv[0]), f1 = b2f((u16)hv[1]);
    float f2 = b2f((u16)hv[2]), f3 = b2f((u16)hv[3]);
    float ss = f0 * ws.x + f1 * ws.y + f2 * ws.z + f3 * ws.w;
    float sd = f0 * wd.x + f1 * wd.y + f2 * wd.z + f3 * wd.w;
#pragma unroll
    for (int m = 1; m < 64; m <<= 1) {
        ss += __shfl_xor(ss, m, 64);
        sd += __shfl_xor(sd, m, 64);
    }
    if (lane == 0) { al_s[n] = ss; al_d[n] = sd; }
}

// per-destination denom: L[d] += exp(leaky(al_s[s]+al_d[d]))
__global__ void edge_L_scatter(const float* __restrict__ al_s,
                               const float* __restrict__ al_d,
                               const int* __restrict__ srcI, const int* __restrict__ dstI,
                               int E, int Etot, float* __restrict__ L) {
    int e = blockIdx.x * blockDim.x + threadIdx.x;
    if (e < Etot) {
        int s = (e < E) ? srcI[e] : (e - E);
        int d = (e < E) ? dstI[e] : (e - E);
        float v = al_s[s] + al_d[d];
        v = (v > 0.f) ? v : NEG_SLOPE * v;
        atomicAdd(&L[d], expf(v));
    }
}

// per-source total attention weight: w[s] += exp(leaky(...)) / L[d]
__global__ void edge_w_scatter(const float* __restrict__ al_s,
                               const float* __restrict__ al_d,
                               const float* __restrict__ L,
                               const int* __restrict__ srcI, const int* __restrict__ dstI,
                               int E, int Etot, float* __restrict__ w) {
    int e = blockIdx.x * blockDim.x + threadIdx.x;
    if (e < Etot) {
        int s = (e < E) ? srcI[e] : (e - E);
        int d = (e < E) ? dstI[e] : (e - E);
        float v = al_s[s] + al_d[d];
        v = (v > 0.f) ? v : NEG_SLOPE * v;
        atomicAdd(&w[s], expf(v) / (L[d] + 1e-16f));
    }
}

// partial[wave][256] = sum over its nodes of w[n]*ob[n,:]
__global__ __launch_bounds__(256) void wcolsum(const u16* __restrict__ ob,
                                               const float* __restrict__ w, int N,
                                               float* __restrict__ partial) {
    const int lane = threadIdx.x & 63;
    int wv = (blockIdx.x * blockDim.x + threadIdx.x) >> 6;
    int nw = (gridDim.x * blockDim.x) >> 6;
    float a0 = 0.f, a1 = 0.f, a2 = 0.f, a3 = 0.f;
    for (int n = wv; n < N; n += nw) {
        float wn = w[n];
        u16x4 hv = *reinterpret_cast<const u16x4*>(&ob[(size_t)n * 256 + lane * 4]);
        a0 = fmaf(wn, b2f((u16)hv[0]), a0);
        a1 = fmaf(wn, b2f((u16)hv[1]), a1);
        a2 = fmaf(wn, b2f((u16)hv[2]), a2);
        a3 = fmaf(wn, b2f((u16)hv[3]), a3);
    }
    float4 o = {a0, a1, a2, a3};
    *reinterpret_cast<float4*>(&partial[(size_t)wv * 256 + lane * 4]) = o;
}

__global__ void reduce_partial(const float* __restrict__ partial, int nw,
                               float* __restrict__ pp) {
    int k = threadIdx.x;  // 256
    float s = 0.f;
    for (int w = 0; w < nw; ++w) s += partial[(size_t)w * 256 + k];
    pp[k] = s;
}

// out = log_softmax(pp/N @ W3 + b3)
__global__ void final_out(const float* __restrict__ pp, const float* __restrict__ W3,
                          const float* __restrict__ b3, int N, float* __restrict__ out) {
    __shared__ float acc[10];
    int t = threadIdx.x;  // 256
    if (t < 10) acc[t] = 0.f;
    __syncthreads();
    float pk = pp[t] / (float)N;
#pragma unroll
    for (int c = 0; c < 10; ++c) atomicAdd(&acc[c], pk * W3[t * 10 + c]);
    __syncthreads();
    if (t == 0) {
        float p[10];
        float mx = -INFINITY;
        for (int c = 0; c < 10; ++c) {
            p[c] = acc[c] + b3[c];
            mx = fmaxf(mx, p[c]);
        }
        float s = 0.f;
        for (int c = 0; c < 10; ++c) s += expf(p[c] - mx);
        float ls = logf(s);
        for (int c = 0; c < 10; ++c) out[c] = p[c] - mx - ls;
    }
}

extern "C" void kernel_launch(void* const* d_in, const int* in_sizes, int n_in,
                              void* d_out, int out_size, void* d_ws, size_t ws_size,
                              hipStream_t stream) {
    const float* x   = (const float*)d_in[0];
    const int*   ei  = (const int*)d_in[1];
    const float* W1  = (const float*)d_in[2];
    const float* as1 = (const float*)d_in[3];
    const float* ad1 = (const float*)d_in[4];
    const float* b1  = (const float*)d_in[5];
    const float* W2  = (const float*)d_in[6];
    const float* as2 = (const float*)d_in[7];
    const float* ad2 = (const float*)d_in[8];
    const float* b2  = (const float*)d_in[9];
    const float* W3  = (const float*)d_in[10];
    const float* as3 = (const float*)d_in[11];
    const float* ad3 = (const float*)d_in[12];
    const float* b3  = (const float*)d_in[13];
    float* out = (float*)d_out;

    const int N = in_sizes[0] / 128;   // 50000
    const int E = in_sizes[1] / 2;     // 800000
    const int Etot = E + N;
    const int* srcI = ei;
    const int* dstI = ei + E;

    char* base = (char*)d_ws;
    size_t off = 0;
    auto alloc = [&](size_t bytes) {
        void* p = base + off;
        off = (off + bytes + 255) & ~(size_t)255;
        return p;
    };
    u16* x_bf  = (u16*)alloc((size_t)N * 128 * 2);
    u16* h_bf  = (u16*)alloc((size_t)N * 256 * 2);
    u16* oa_bf = (u16*)alloc((size_t)N * 256 * 2);
    u16* ob_bf = (u16*)alloc((size_t)N * 256 * 2);
    u16* w1t   = (u16*)alloc(256 * 128 * 2);
    u16* w2t   = (u16*)alloc(256 * 256 * 2);
    float* al_s = (float*)alloc((size_t)N * 4 * 4);
    float* al_d = (float*)alloc((size_t)N * 4 * 4);
    int* cnt    = (int*)alloc((size_t)N * 4);
    int* rp     = (int*)alloc((size_t)(N + 1) * 4);
    int* cursor = (int*)alloc((size_t)N * 4);
    int* srcp   = (int*)alloc((size_t)Etot * 4);
    float* was   = (float*)alloc(256 * 4);
    float* wad   = (float*)alloc(256 * 4);
    float* Lbuf  = (float*)alloc((size_t)N * 4);
    float* wbuf  = (float*)alloc((size_t)N * 4);
    float* partial = (float*)alloc((size_t)512 * 256 * 4);
    float* pp    = (float*)alloc(256 * 4);

    // ---- preprocessing: casts, transposes, CSR ----
    cast_f2b4<<<(N * 128 / 4 + 255) / 256, 256, 0, stream>>>(x, x_bf, N * 128 / 4);
    transpose_w<<<(128 * 256 + 255) / 256, 256, 0, stream>>>(W1, w1t, 128, 256);
    transpose_w<<<(256 * 256 + 255) / 256, 256, 0, stream>>>(W2, w2t, 256, 256);
    hipMemsetAsync(cnt, 0, (size_t)N * sizeof(int), stream);
    deg_hist<<<(Etot + 255) / 256, 256, 0, stream>>>(dstI, E, Etot, cnt);
    scan_excl4<<<1, 1024, 0, stream>>>(cnt, rp, cursor, N);
    csr_scatter<<<(Etot + 255) / 256, 256, 0, stream>>>(srcI, dstI, E, Etot, cursor, srcp);

    const int FUSED_BLOCKS = (N + 3) / 4;
    const int GX = (N + 127) / 128;

    // ---- layer 1: x_bf[N,128] -> oa_bf[N,256], ELU ----
    {
        dim3 g(GX, 2);
        gemm_mfma<<<g, 256, 0, stream>>>(x_bf, w1t, h_bf, N, 128, 256);
        compute_al_b<<<(N * 4 + 255) / 256, 256, 0, stream>>>(h_bf, as1, ad1, N, al_s, al_d);
        gat_fused_h4<true><<<FUSED_BLOCKS, 256, 0, stream>>>(
            h_bf, al_s, al_d, b1, rp, srcp, N, oa_bf);
    }
    // ---- layer 2: oa_bf -> ob_bf, ELU ----
    {
        dim3 g(GX, 2);
        gemm_mfma<<<g, 256, 0, stream>>>(oa_bf, w2t, h_bf, N, 256, 256);
        compute_al_b<<<(N * 4 + 255) / 256, 256, 0, stream>>>(h_bf, as2, ad2, N, al_s, al_d);
        gat_fused_h4<true><<<FUSED_BLOCKS, 256, 0, stream>>>(
            h_bf, al_s, al_d, b2, rp, srcp, N, ob_bf);
    }
    // ---- layer 3 (linear-collapsed): pooled = (1/N * sum_s w_s ob_s) @ W3 + b3
    {
        make_wasd<<<1, 256, 0, stream>>>(W3, as3, ad3, was, wad);
        compute_al3<<<(N + 3) / 4, 256, 0, stream>>>(ob_bf, was, wad, N, al_s, al_d);
        hipMemsetAsync(Lbuf, 0, (size_t)N * sizeof(float), stream);
        hipMemsetAsync(wbuf, 0, (size_t)N * sizeof(float), stream);
        edge_L_scatter<<<(Etot + 255) / 256, 256, 0, stream>>>(al_s, al_d, srcI, dstI,
                                                               E, Etot, Lbuf);
        edge_w_scatter<<<(Etot + 255) / 256, 256, 0, stream>>>(al_s, al_d, Lbuf, srcI,
                                                               dstI, E, Etot, wbuf);
        wcolsum<<<128, 256, 0, stream>>>(ob_bf, wbuf, N, partial);
        reduce_partial<<<1, 256, 0, stream>>>(partial, 512, pp);
        final_out<<<1, 256, 0, stream>>>(pp, W3, b3, N, out);
    }
}

// Round 6
// 575.535 us; speedup vs baseline: 1.1180x; 1.1180x over previous
//
#include <hip/hip_runtime.h>
#include <math.h>

#define NEG_SLOPE 0.2f

typedef __attribute__((ext_vector_type(8))) short bf16x8;
typedef __attribute__((ext_vector_type(4))) float f32x4;
typedef unsigned short u16;
typedef __attribute__((ext_vector_type(4))) unsigned short u16x4;

__device__ __forceinline__ float b2f(u16 u) {
    return __uint_as_float(((unsigned)u) << 16);
}
__device__ __forceinline__ u16 f2b(float f) {
    unsigned u = __float_as_uint(f);
    unsigned r = (u + 0x7fffu + ((u >> 16) & 1u)) >> 16;
    return (u16)r;
}

// ---------------- casts / transposes ----------------
__global__ void cast_f2b4(const float* __restrict__ in, u16* __restrict__ out, int n4) {
    int i = blockIdx.x * blockDim.x + threadIdx.x;
    if (i < n4) {
        float4 v = *reinterpret_cast<const float4*>(&in[i * 4]);
        u16x4 o;
        o[0] = f2b(v.x); o[1] = f2b(v.y); o[2] = f2b(v.z); o[3] = f2b(v.w);
        *reinterpret_cast<u16x4*>(&out[i * 4]) = o;
    }
}

// W[K][M] fp32 -> Wt[M][K] bf16
__global__ void transpose_w(const float* __restrict__ W, u16* __restrict__ Wt,
                            int K, int M) {
    int i = blockIdx.x * blockDim.x + threadIdx.x;
    if (i < K * M) {
        int m = i / K, k = i - m * K;
        Wt[i] = f2b(W[(size_t)k * M + m]);
    }
}

// ---------------- MFMA GEMM: C[N,M] bf16 = A[N,K] bf16 * Bt[M,K]^T ----------
__global__ __launch_bounds__(256) void gemm_mfma(
        const u16* __restrict__ A, const u16* __restrict__ Bt,
        u16* __restrict__ C, int N, int K, int M) {
    __shared__ u16 As[128 * 64];
    __shared__ u16 Bs[128 * 64];
    const int tid = threadIdx.x;
    const int lane = tid & 63;
    const int wid = tid >> 6;
    const int wr = wid >> 1, wc = wid & 1;
    const int row0 = blockIdx.x * 128;
    const int col0 = blockIdx.y * 128;
    f32x4 acc[4][4] = {};
    for (int k0 = 0; k0 < K; k0 += 64) {
        if (k0) __syncthreads();
#pragma unroll
        for (int i = 0; i < 4; ++i) {
            int chunk = i * 256 + tid;
            int row = chunk >> 3;
            int slot = chunk & 7;
            int grow = row0 + row; if (grow >= N) grow = N - 1;
            bf16x8 v = *reinterpret_cast<const bf16x8*>(&A[(size_t)grow * K + k0 + slot * 8]);
            int swz = (chunk & ~7) | (slot ^ (row & 7));
            *reinterpret_cast<bf16x8*>(&As[swz * 8]) = v;
        }
#pragma unroll
        for (int i = 0; i < 4; ++i) {
            int chunk = i * 256 + tid;
            int row = chunk >> 3;
            int slot = chunk & 7;
            int gcol = col0 + row;
            bf16x8 v = *reinterpret_cast<const bf16x8*>(&Bt[(size_t)gcol * K + k0 + slot * 8]);
            int swz = (chunk & ~7) | (slot ^ (row & 7));
            *reinterpret_cast<bf16x8*>(&Bs[swz * 8]) = v;
        }
        __syncthreads();
#pragma unroll
        for (int kk = 0; kk < 2; ++kk) {
            bf16x8 ax[4], bx[4];
#pragma unroll
            for (int m = 0; m < 4; ++m) {
                int row = wr * 64 + m * 16 + (lane & 15);
                int slot = kk * 4 + (lane >> 4);
                ax[m] = *reinterpret_cast<const bf16x8*>(&As[(row * 8 + (slot ^ (row & 7))) * 8]);
            }
#pragma unroll
            for (int n = 0; n < 4; ++n) {
                int row = wc * 64 + n * 16 + (lane & 15);
                int slot = kk * 4 + (lane >> 4);
                bx[n] = *reinterpret_cast<const bf16x8*>(&Bs[(row * 8 + (slot ^ (row & 7))) * 8]);
            }
#pragma unroll
            for (int m = 0; m < 4; ++m)
#pragma unroll
                for (int n = 0; n < 4; ++n)
                    acc[m][n] = __builtin_amdgcn_mfma_f32_16x16x32_bf16(
                        ax[m], bx[n], acc[m][n], 0, 0, 0);
        }
    }
    const int crow = row0 + wr * 64;
    const int ccol = col0 + wc * 64;
#pragma unroll
    for (int m = 0; m < 4; ++m)
#pragma unroll
        for (int n = 0; n < 4; ++n)
#pragma unroll
            for (int r = 0; r < 4; ++r) {
                int rg = crow + m * 16 + (lane >> 4) * 4 + r;
                int cg = ccol + n * 16 + (lane & 15);
                if (rg < N) C[(size_t)rg * M + cg] = f2b(acc[m][n][r]);
            }
}

// ---------------- per-node attention dots (bf16 h, H=4, C=64) --------------
__global__ void compute_al_b(const u16* __restrict__ h, const float* __restrict__ a_s,
                             const float* __restrict__ a_d, int N,
                             float* __restrict__ al_s, float* __restrict__ al_d) {
    int i = blockIdx.x * blockDim.x + threadIdx.x;   // n*4 + head
    if (i < N * 4) {
        int hh = i & 3;
        const u16* hp = h + (size_t)(i >> 2) * 256 + hh * 64;
        const float* as = a_s + hh * 64;
        const float* ad = a_d + hh * 64;
        float ss = 0.f, sd = 0.f;
        for (int c0 = 0; c0 < 64; c0 += 8) {
            bf16x8 v = *reinterpret_cast<const bf16x8*>(&hp[c0]);
#pragma unroll
            for (int j = 0; j < 8; ++j) {
                float f = b2f((u16)v[j]);
                ss = fmaf(f, as[c0 + j], ss);
                sd = fmaf(f, ad[c0 + j], sd);
            }
        }
        al_s[i] = ss; al_d[i] = sd;
    }
}

// ---------------- CSR build ----------------
__global__ void deg_hist(const int* __restrict__ dstI, int E, int Etot,
                         int* __restrict__ cnt) {
    int e = blockIdx.x * blockDim.x + threadIdx.x;
    if (e < Etot) {
        int d = (e < E) ? dstI[e] : (e - E);
        atomicAdd(&cnt[d], 1);
    }
}

// single-block exclusive scan, 4 elements/thread (writes rp AND cursor)
__global__ __launch_bounds__(1024) void scan_excl4(const int* __restrict__ cnt,
                                                   int* __restrict__ rp,
                                                   int* __restrict__ cursor, int N) {
    __shared__ int wsum[16];
    __shared__ int carry_s;
    int lane = threadIdx.x & 63;
    int wid = threadIdx.x >> 6;
    if (threadIdx.x == 0) carry_s = 0;
    __syncthreads();
    for (int base = 0; base < N; base += 4096) {
        int idx = base + (int)threadIdx.x * 4;
        int a0 = 0, a1 = 0, a2 = 0, a3 = 0;
        if (idx + 3 < N) {
            int4 v = *reinterpret_cast<const int4*>(&cnt[idx]);
            a0 = v.x; a1 = v.y; a2 = v.z; a3 = v.w;
        } else {
            if (idx < N)     a0 = cnt[idx];
            if (idx + 1 < N) a1 = cnt[idx + 1];
            if (idx + 2 < N) a2 = cnt[idx + 2];
        }
        int p1 = a0 + a1, p2 = p1 + a2, p3 = p2 + a3;
        int x = p3;
#pragma unroll
        for (int ofs = 1; ofs < 64; ofs <<= 1) {
            int t = __shfl_up(x, ofs, 64);
            if (lane >= ofs) x += t;
        }
        if (lane == 63) wsum[wid] = x;
        __syncthreads();
        if (wid == 0) {
            int y = (lane < 16) ? wsum[lane] : 0;
#pragma unroll
            for (int ofs = 1; ofs < 16; ofs <<= 1) {
                int t = __shfl_up(y, ofs, 64);
                if (lane >= ofs) y += t;
            }
            if (lane < 16) wsum[lane] = y;
        }
        __syncthreads();
        int wofs = (wid > 0) ? wsum[wid - 1] : 0;
        int carry = carry_s;
        int excl = carry + wofs + (x - p3);
        if (idx < N)     { rp[idx] = excl;          cursor[idx] = excl; }
        if (idx + 1 < N) { rp[idx + 1] = excl + a0; cursor[idx + 1] = excl + a0; }
        if (idx + 2 < N) { rp[idx + 2] = excl + p1; cursor[idx + 2] = excl + p1; }
        if (idx + 3 < N) { rp[idx + 3] = excl + p2; cursor[idx + 3] = excl + p2; }
        __syncthreads();
        if (threadIdx.x == 1023) carry_s = carry + wsum[15];
        __syncthreads();
    }
    if (threadIdx.x == 0) rp[N] = carry_s;
}

__global__ void csr_scatter(const int* __restrict__ srcI, const int* __restrict__ dstI,
                            int E, int Etot, int* __restrict__ cursor,
                            int* __restrict__ srcp) {
    int e = blockIdx.x * blockDim.x + threadIdx.x;
    if (e < Etot) {
        int s, d;
        if (e < E) { s = srcI[e]; d = dstI[e]; }
        else       { s = e - E;   d = e - E; }
        int pos = atomicAdd(&cursor[d], 1);
        srcp[pos] = s;
    }
}

// ---------------- single-pass fused aggregate, H=4, C=64 --------------------
template<bool ELU>
__global__ __launch_bounds__(256) void gat_fused_h4(
        const u16* __restrict__ h, const float* __restrict__ al_s,
        const float* __restrict__ al_d, const float* __restrict__ b,
        const int* __restrict__ rp, const int* __restrict__ srcp,
        int N, u16* __restrict__ out) {
    const int lane = threadIdx.x & 63;
    const int head = lane >> 4;
    int w = (blockIdx.x * blockDim.x + threadIdx.x) >> 6;
    int nw = (gridDim.x * blockDim.x) >> 6;
    for (int d = w; d < N; d += nw) {
        int i = rp[d], end = rp[d + 1];
        float ald = al_d[d * 4 + head];
        float acc0 = 0.f, acc1 = 0.f, acc2 = 0.f, acc3 = 0.f, L = 0.f;
        for (; i + 2 <= end; i += 2) {
            int s0 = srcp[i], s1 = srcp[i + 1];
            u16x4 h0 = *reinterpret_cast<const u16x4*>(&h[(size_t)s0 * 256 + lane * 4]);
            u16x4 h1 = *reinterpret_cast<const u16x4*>(&h[(size_t)s1 * 256 + lane * 4]);
            float v0 = al_s[s0 * 4 + head] + ald;
            float v1 = al_s[s1 * 4 + head] + ald;
            v0 = (v0 > 0.f) ? v0 : NEG_SLOPE * v0;
            v1 = (v1 > 0.f) ? v1 : NEG_SLOPE * v1;
            float e0 = expf(v0), e1 = expf(v1);
            L += e0 + e1;
            acc0 = fmaf(e0, b2f((u16)h0[0]), acc0);
            acc1 = fmaf(e0, b2f((u16)h0[1]), acc1);
            acc2 = fmaf(e0, b2f((u16)h0[2]), acc2);
            acc3 = fmaf(e0, b2f((u16)h0[3]), acc3);
            acc0 = fmaf(e1, b2f((u16)h1[0]), acc0);
            acc1 = fmaf(e1, b2f((u16)h1[1]), acc1);
            acc2 = fmaf(e1, b2f((u16)h1[2]), acc2);
            acc3 = fmaf(e1, b2f((u16)h1[3]), acc3);
        }
        if (i < end) {
            int s0 = srcp[i];
            u16x4 h0 = *reinterpret_cast<const u16x4*>(&h[(size_t)s0 * 256 + lane * 4]);
            float v0 = al_s[s0 * 4 + head] + ald;
            v0 = (v0 > 0.f) ? v0 : NEG_SLOPE * v0;
            float e0 = expf(v0);
            L += e0;
            acc0 = fmaf(e0, b2f((u16)h0[0]), acc0);
            acc1 = fmaf(e0, b2f((u16)h0[1]), acc1);
            acc2 = fmaf(e0, b2f((u16)h0[2]), acc2);
            acc3 = fmaf(e0, b2f((u16)h0[3]), acc3);
        }
        float inv = 1.f / (L + 1e-16f);
        float4 bb = *reinterpret_cast<const float4*>(&b[lane * 4]);
        float o0 = fmaf(acc0, inv, bb.x);
        float o1 = fmaf(acc1, inv, bb.y);
        float o2 = fmaf(acc2, inv, bb.z);
        float o3 = fmaf(acc3, inv, bb.w);
        if (ELU) {
            o0 = (o0 > 0.f) ? o0 : expm1f(o0);
            o1 = (o1 > 0.f) ? o1 : expm1f(o1);
            o2 = (o2 > 0.f) ? o2 : expm1f(o2);
            o3 = (o3 > 0.f) ? o3 : expm1f(o3);
        }
        u16x4 ov;
        ov[0] = f2b(o0); ov[1] = f2b(o1); ov[2] = f2b(o2); ov[3] = f2b(o3);
        *reinterpret_cast<u16x4*>(&out[(size_t)d * 256 + lane * 4]) = ov;
    }
}

// ================= layer-3 linear-collapse path =============================
// was[k] = sum_c W3[k][c]*a_src3[c];  wad likewise
__global__ void make_wasd(const float* __restrict__ W3, const float* __restrict__ as3,
                          const float* __restrict__ ad3,
                          float* __restrict__ was, float* __restrict__ wad) {
    int k = threadIdx.x;  // 256
    float ss = 0.f, sd = 0.f;
#pragma unroll
    for (int c = 0; c < 10; ++c) {
        float w = W3[k * 10 + c];
        ss = fmaf(w, as3[c], ss);
        sd = fmaf(w, ad3[c], sd);
    }
    was[k] = ss; wad[k] = sd;
}

// al_s[n] = ob[n,:] . was ;  al_d[n] = ob[n,:] . wad  (one wave per node)
__global__ __launch_bounds__(256) void compute_al3(
        const u16* __restrict__ ob, const float* __restrict__ was,
        const float* __restrict__ wad, int N,
        float* __restrict__ al_s, float* __restrict__ al_d) {
    const int lane = threadIdx.x & 63;
    int n = (blockIdx.x * blockDim.x + threadIdx.x) >> 6;
    if (n >= N) return;
    u16x4 hv = *reinterpret_cast<const u16x4*>(&ob[(size_t)n * 256 + lane * 4]);
    float4 ws = *reinterpret_cast<const float4*>(&was[lane * 4]);
    float4 wd = *reinterpret_cast<const float4*>(&wad[lane * 4]);
    float f0 = b2f((u16)hv[0]), f1 = b2f((u16)hv[1]);
    float f2 = b2f((u16)hv[2]), f3 = b2f((u16)hv[3]);
    float ss = f0 * ws.x + f1 * ws.y + f2 * ws.z + f3 * ws.w;
    float sd = f0 * wd.x + f1 * wd.y + f2 * wd.z + f3 * wd.w;
#pragma unroll
    for (int m = 1; m < 64; m <<= 1) {
        ss += __shfl_xor(ss, m, 64);
        sd += __shfl_xor(sd, m, 64);
    }
    if (lane == 0) { al_s[n] = ss; al_d[n] = sd; }
}

// per-destination denom: L[d] += exp(leaky(al_s[s]+al_d[d]))
__global__ void edge_L_scatter(const float* __restrict__ al_s,
                               const float* __restrict__ al_d,
                               const int* __restrict__ srcI, const int* __restrict__ dstI,
                               int E, int Etot, float* __restrict__ L) {
    int e = blockIdx.x * blockDim.x + threadIdx.x;
    if (e < Etot) {
        int s = (e < E) ? srcI[e] : (e - E);
        int d = (e < E) ? dstI[e] : (e - E);
        float v = al_s[s] + al_d[d];
        v = (v > 0.f) ? v : NEG_SLOPE * v;
        atomicAdd(&L[d], expf(v));
    }
}

// per-source total attention weight: w[s] += exp(leaky(...)) / L[d]
__global__ void edge_w_scatter(const float* __restrict__ al_s,
                               const float* __restrict__ al_d,
                               const float* __restrict__ L,
                               const int* __restrict__ srcI, const int* __restrict__ dstI,
                               int E, int Etot, float* __restrict__ w) {
    int e = blockIdx.x * blockDim.x + threadIdx.x;
    if (e < Etot) {
        int s = (e < E) ? srcI[e] : (e - E);
        int d = (e < E) ? dstI[e] : (e - E);
        float v = al_s[s] + al_d[d];
        v = (v > 0.f) ? v : NEG_SLOPE * v;
        atomicAdd(&w[s], expf(v) / (L[d] + 1e-16f));
    }
}

// pp[256] += sum over this wave's nodes of w[n]*ob[n,:]  (atomic epilogue)
__global__ __launch_bounds__(256) void wcolsum(const u16* __restrict__ ob,
                                               const float* __restrict__ w, int N,
                                               float* __restrict__ pp) {
    const int lane = threadIdx.x & 63;
    int wv = (blockIdx.x * blockDim.x + threadIdx.x) >> 6;
    int nw = (gridDim.x * blockDim.x) >> 6;
    float a0 = 0.f, a1 = 0.f, a2 = 0.f, a3 = 0.f;
    for (int n = wv; n < N; n += nw) {
        float wn = w[n];
        u16x4 hv = *reinterpret_cast<const u16x4*>(&ob[(size_t)n * 256 + lane * 4]);
        a0 = fmaf(wn, b2f((u16)hv[0]), a0);
        a1 = fmaf(wn, b2f((u16)hv[1]), a1);
        a2 = fmaf(wn, b2f((u16)hv[2]), a2);
        a3 = fmaf(wn, b2f((u16)hv[3]), a3);
    }
    atomicAdd(&pp[lane * 4 + 0], a0);
    atomicAdd(&pp[lane * 4 + 1], a1);
    atomicAdd(&pp[lane * 4 + 2], a2);
    atomicAdd(&pp[lane * 4 + 3], a3);
}

// out = log_softmax(pp/N @ W3 + b3)
__global__ void final_out(const float* __restrict__ pp, const float* __restrict__ W3,
                          const float* __restrict__ b3, int N, float* __restrict__ out) {
    __shared__ float acc[10];
    int t = threadIdx.x;  // 256
    if (t < 10) acc[t] = 0.f;
    __syncthreads();
    float pk = pp[t] / (float)N;
#pragma unroll
    for (int c = 0; c < 10; ++c) atomicAdd(&acc[c], pk * W3[t * 10 + c]);
    __syncthreads();
    if (t == 0) {
        float p[10];
        float mx = -INFINITY;
        for (int c = 0; c < 10; ++c) {
            p[c] = acc[c] + b3[c];
            mx = fmaxf(mx, p[c]);
        }
        float s = 0.f;
        for (int c = 0; c < 10; ++c) s += expf(p[c] - mx);
        float ls = logf(s);
        for (int c = 0; c < 10; ++c) out[c] = p[c] - mx - ls;
    }
}

extern "C" void kernel_launch(void* const* d_in, const int* in_sizes, int n_in,
                              void* d_out, int out_size, void* d_ws, size_t ws_size,
                              hipStream_t stream) {
    const float* x   = (const float*)d_in[0];
    const int*   ei  = (const int*)d_in[1];
    const float* W1  = (const float*)d_in[2];
    const float* as1 = (const float*)d_in[3];
    const float* ad1 = (const float*)d_in[4];
    const float* b1  = (const float*)d_in[5];
    const float* W2  = (const float*)d_in[6];
    const float* as2 = (const float*)d_in[7];
    const float* ad2 = (const float*)d_in[8];
    const float* b2  = (const float*)d_in[9];
    const float* W3  = (const float*)d_in[10];
    const float* as3 = (const float*)d_in[11];
    const float* ad3 = (const float*)d_in[12];
    const float* b3  = (const float*)d_in[13];
    float* out = (float*)d_out;

    const int N = in_sizes[0] / 128;   // 50000
    const int E = in_sizes[1] / 2;     // 800000
    const int Etot = E + N;
    const int* srcI = ei;
    const int* dstI = ei + E;

    char* base = (char*)d_ws;
    size_t off = 0;
    auto alloc = [&](size_t bytes) {
        void* p = base + off;
        off = (off + bytes + 255) & ~(size_t)255;
        return p;
    };
    u16* x_bf  = (u16*)alloc((size_t)N * 128 * 2);
    u16* h_bf  = (u16*)alloc((size_t)N * 256 * 2);
    u16* oa_bf = (u16*)alloc((size_t)N * 256 * 2);
    u16* ob_bf = (u16*)alloc((size_t)N * 256 * 2);
    u16* w1t   = (u16*)alloc(256 * 128 * 2);
    u16* w2t   = (u16*)alloc(256 * 256 * 2);
    float* al_s = (float*)alloc((size_t)N * 4 * 4);
    float* al_d = (float*)alloc((size_t)N * 4 * 4);
    int* cnt    = (int*)alloc((size_t)N * 4);
    int* rp     = (int*)alloc((size_t)(N + 1) * 4);
    int* cursor = (int*)alloc((size_t)N * 4);
    int* srcp   = (int*)alloc((size_t)Etot * 4);
    float* was   = (float*)alloc(256 * 4);
    float* wad   = (float*)alloc(256 * 4);
    float* Lbuf  = (float*)alloc((size_t)N * 4);
    float* wbuf  = (float*)alloc((size_t)N * 4);
    float* pp    = (float*)alloc(256 * 4);

    // ---- preprocessing: casts, transposes, CSR ----
    cast_f2b4<<<(N * 128 / 4 + 255) / 256, 256, 0, stream>>>(x, x_bf, N * 128 / 4);
    transpose_w<<<(128 * 256 + 255) / 256, 256, 0, stream>>>(W1, w1t, 128, 256);
    transpose_w<<<(256 * 256 + 255) / 256, 256, 0, stream>>>(W2, w2t, 256, 256);
    hipMemsetAsync(cnt, 0, (size_t)N * sizeof(int), stream);
    deg_hist<<<(Etot + 255) / 256, 256, 0, stream>>>(dstI, E, Etot, cnt);
    scan_excl4<<<1, 1024, 0, stream>>>(cnt, rp, cursor, N);
    csr_scatter<<<(Etot + 255) / 256, 256, 0, stream>>>(srcI, dstI, E, Etot, cursor, srcp);

    const int FUSED_BLOCKS = (N + 3) / 4;
    const int GX = (N + 127) / 128;

    // ---- layer 1: x_bf[N,128] -> oa_bf[N,256], ELU ----
    {
        dim3 g(GX, 2);
        gemm_mfma<<<g, 256, 0, stream>>>(x_bf, w1t, h_bf, N, 128, 256);
        compute_al_b<<<(N * 4 + 255) / 256, 256, 0, stream>>>(h_bf, as1, ad1, N, al_s, al_d);
        gat_fused_h4<true><<<FUSED_BLOCKS, 256, 0, stream>>>(
            h_bf, al_s, al_d, b1, rp, srcp, N, oa_bf);
    }
    // ---- layer 2: oa_bf -> ob_bf, ELU ----
    {
        dim3 g(GX, 2);
        gemm_mfma<<<g, 256, 0, stream>>>(oa_bf, w2t, h_bf, N, 256, 256);
        compute_al_b<<<(N * 4 + 255) / 256, 256, 0, stream>>>(h_bf, as2, ad2, N, al_s, al_d);
        gat_fused_h4<true><<<FUSED_BLOCKS, 256, 0, stream>>>(
            h_bf, al_s, al_d, b2, rp, srcp, N, ob_bf);
    }
    // ---- layer 3 (linear-collapsed): pooled = (1/N * sum_s w_s ob_s) @ W3 + b3
    {
        make_wasd<<<1, 256, 0, stream>>>(W3, as3, ad3, was, wad);
        compute_al3<<<(N + 3) / 4, 256, 0, stream>>>(ob_bf, was, wad, N, al_s, al_d);
        hipMemsetAsync(Lbuf, 0, (size_t)N * sizeof(float), stream);
        hipMemsetAsync(wbuf, 0, (size_t)N * sizeof(float), stream);
        hipMemsetAsync(pp, 0, 256 * sizeof(float), stream);
        edge_L_scatter<<<(Etot + 255) / 256, 256, 0, stream>>>(al_s, al_d, srcI, dstI,
                                                               E, Etot, Lbuf);
        edge_w_scatter<<<(Etot + 255) / 256, 256, 0, stream>>>(al_s, al_d, Lbuf, srcI,
                                                               dstI, E, Etot, wbuf);
        wcolsum<<<128, 256, 0, stream>>>(ob_bf, wbuf, N, pp);
        final_out<<<1, 256, 0, stream>>>(pp, W3, b3, N, out);
    }
}

// Round 7
// 487.979 us; speedup vs baseline: 1.3186x; 1.1794x over previous
//
#include <hip/hip_runtime.h>
#include <math.h>

#define NEG_SLOPE 0.2f

typedef __attribute__((ext_vector_type(8))) short bf16x8;
typedef __attribute__((ext_vector_type(4))) float f32x4;
typedef __attribute__((ext_vector_type(2))) float f32x2;
typedef unsigned short u16;
typedef __attribute__((ext_vector_type(4))) unsigned short u16x4;

__device__ __forceinline__ float b2f(u16 u) {
    return __uint_as_float(((unsigned)u) << 16);
}
__device__ __forceinline__ u16 f2b(float f) {
    unsigned u = __float_as_uint(f);
    unsigned r = (u + 0x7fffu + ((u >> 16) & 1u)) >> 16;
    return (u16)r;
}

// ---------------- fused prep: cast x, transpose W1/W2, zero scratch --------
// block ranges: [0,B0) cast x; [B0,B1) w1t; [B1,B2) w2t; [B2,B3) zero
__global__ void prep(const float* __restrict__ x, u16* __restrict__ x_bf, int n4,
                     const float* __restrict__ W1, u16* __restrict__ w1t,
                     const float* __restrict__ W2, u16* __restrict__ w2t,
                     int* __restrict__ zero_base, int nzero,
                     int B0, int B1, int B2) {
    int blk = blockIdx.x;
    if (blk < B0) {
        int i = blk * 256 + threadIdx.x;
        if (i < n4) {
            float4 v = *reinterpret_cast<const float4*>(&x[i * 4]);
            u16x4 o;
            o[0] = f2b(v.x); o[1] = f2b(v.y); o[2] = f2b(v.z); o[3] = f2b(v.w);
            *reinterpret_cast<u16x4*>(&x_bf[i * 4]) = o;
        }
    } else if (blk < B1) {
        int i = (blk - B0) * 256 + threadIdx.x;  // Wt index, [M][K] with K=128,M=256
        if (i < 128 * 256) {
            int m = i >> 7, k = i & 127;
            w1t[i] = f2b(W1[(size_t)k * 256 + m]);
        }
    } else if (blk < B2) {
        int i = (blk - B1) * 256 + threadIdx.x;  // K=256,M=256
        if (i < 256 * 256) {
            int m = i >> 8, k = i & 255;
            w2t[i] = f2b(W2[(size_t)k * 256 + m]);
        }
    } else {
        int i = (blk - B2) * 256 + threadIdx.x;
        if (i < nzero) zero_base[i] = 0;
    }
}

// ---------------- MFMA GEMM: C[N,M] bf16 = A[N,K] bf16 * Bt[M,K]^T ----------
__global__ __launch_bounds__(256) void gemm_mfma(
        const u16* __restrict__ A, const u16* __restrict__ Bt,
        u16* __restrict__ C, int N, int K, int M) {
    __shared__ u16 As[128 * 64];
    __shared__ u16 Bs[128 * 64];
    const int tid = threadIdx.x;
    const int lane = tid & 63;
    const int wid = tid >> 6;
    const int wr = wid >> 1, wc = wid & 1;
    const int row0 = blockIdx.x * 128;
    const int col0 = blockIdx.y * 128;
    f32x4 acc[4][4] = {};
    for (int k0 = 0; k0 < K; k0 += 64) {
        if (k0) __syncthreads();
#pragma unroll
        for (int i = 0; i < 4; ++i) {
            int chunk = i * 256 + tid;
            int row = chunk >> 3;
            int slot = chunk & 7;
            int grow = row0 + row; if (grow >= N) grow = N - 1;
            bf16x8 v = *reinterpret_cast<const bf16x8*>(&A[(size_t)grow * K + k0 + slot * 8]);
            int swz = (chunk & ~7) | (slot ^ (row & 7));
            *reinterpret_cast<bf16x8*>(&As[swz * 8]) = v;
        }
#pragma unroll
        for (int i = 0; i < 4; ++i) {
            int chunk = i * 256 + tid;
            int row = chunk >> 3;
            int slot = chunk & 7;
            int gcol = col0 + row;
            bf16x8 v = *reinterpret_cast<const bf16x8*>(&Bt[(size_t)gcol * K + k0 + slot * 8]);
            int swz = (chunk & ~7) | (slot ^ (row & 7));
            *reinterpret_cast<bf16x8*>(&Bs[swz * 8]) = v;
        }
        __syncthreads();
#pragma unroll
        for (int kk = 0; kk < 2; ++kk) {
            bf16x8 ax[4], bx[4];
#pragma unroll
            for (int m = 0; m < 4; ++m) {
                int row = wr * 64 + m * 16 + (lane & 15);
                int slot = kk * 4 + (lane >> 4);
                ax[m] = *reinterpret_cast<const bf16x8*>(&As[(row * 8 + (slot ^ (row & 7))) * 8]);
            }
#pragma unroll
            for (int n = 0; n < 4; ++n) {
                int row = wc * 64 + n * 16 + (lane & 15);
                int slot = kk * 4 + (lane >> 4);
                bx[n] = *reinterpret_cast<const bf16x8*>(&Bs[(row * 8 + (slot ^ (row & 7))) * 8]);
            }
#pragma unroll
            for (int m = 0; m < 4; ++m)
#pragma unroll
                for (int n = 0; n < 4; ++n)
                    acc[m][n] = __builtin_amdgcn_mfma_f32_16x16x32_bf16(
                        ax[m], bx[n], acc[m][n], 0, 0, 0);
        }
    }
    const int crow = row0 + wr * 64;
    const int ccol = col0 + wc * 64;
#pragma unroll
    for (int m = 0; m < 4; ++m)
#pragma unroll
        for (int n = 0; n < 4; ++n)
#pragma unroll
            for (int r = 0; r < 4; ++r) {
                int rg = crow + m * 16 + (lane >> 4) * 4 + r;
                int cg = ccol + n * 16 + (lane & 15);
                if (rg < N) C[(size_t)rg * M + cg] = f2b(acc[m][n][r]);
            }
}

// ------- per-node attention dots + fp8 re-encode of h (H=4, C=64) ----------
__global__ void compute_al_cast(const u16* __restrict__ h, const float* __restrict__ a_s,
                                const float* __restrict__ a_d, int N,
                                float* __restrict__ al_s, float* __restrict__ al_d,
                                unsigned* __restrict__ h8) {
    int i = blockIdx.x * blockDim.x + threadIdx.x;   // n*4 + head
    if (i < N * 4) {
        int hh = i & 3;
        const u16* hp = h + (size_t)(i >> 2) * 256 + hh * 64;
        const float* as = a_s + hh * 64;
        const float* ad = a_d + hh * 64;
        unsigned* op = h8 + (size_t)(i >> 2) * 64 + hh * 16;
        float ss = 0.f, sd = 0.f;
#pragma unroll
        for (int c0 = 0; c0 < 64; c0 += 8) {
            bf16x8 v = *reinterpret_cast<const bf16x8*>(&hp[c0]);
            float f[8];
#pragma unroll
            for (int j = 0; j < 8; ++j) {
                f[j] = b2f((u16)v[j]);
                ss = fmaf(f[j], as[c0 + j], ss);
                sd = fmaf(f[j], ad[c0 + j], sd);
            }
            int w0 = 0, w1 = 0;
            w0 = __builtin_amdgcn_cvt_pk_fp8_f32(f[0], f[1], w0, false);
            w0 = __builtin_amdgcn_cvt_pk_fp8_f32(f[2], f[3], w0, true);
            w1 = __builtin_amdgcn_cvt_pk_fp8_f32(f[4], f[5], w1, false);
            w1 = __builtin_amdgcn_cvt_pk_fp8_f32(f[6], f[7], w1, true);
            op[c0 / 4]     = (unsigned)w0;
            op[c0 / 4 + 1] = (unsigned)w1;
        }
        al_s[i] = ss; al_d[i] = sd;
    }
}

// ---------------- CSR build ----------------
__global__ void deg_hist(const int* __restrict__ dstI, int E, int Etot,
                         int* __restrict__ cnt) {
    int e = blockIdx.x * blockDim.x + threadIdx.x;
    if (e < Etot) {
        int d = (e < E) ? dstI[e] : (e - E);
        atomicAdd(&cnt[d], 1);
    }
}

// single-block exclusive scan, 4 elements/thread (writes rp AND cursor)
__global__ __launch_bounds__(1024) void scan_excl4(const int* __restrict__ cnt,
                                                   int* __restrict__ rp,
                                                   int* __restrict__ cursor, int N) {
    __shared__ int wsum[16];
    __shared__ int carry_s;
    int lane = threadIdx.x & 63;
    int wid = threadIdx.x >> 6;
    if (threadIdx.x == 0) carry_s = 0;
    __syncthreads();
    for (int base = 0; base < N; base += 4096) {
        int idx = base + (int)threadIdx.x * 4;
        int a0 = 0, a1 = 0, a2 = 0, a3 = 0;
        if (idx + 3 < N) {
            int4 v = *reinterpret_cast<const int4*>(&cnt[idx]);
            a0 = v.x; a1 = v.y; a2 = v.z; a3 = v.w;
        } else {
            if (idx < N)     a0 = cnt[idx];
            if (idx + 1 < N) a1 = cnt[idx + 1];
            if (idx + 2 < N) a2 = cnt[idx + 2];
        }
        int p1 = a0 + a1, p2 = p1 + a2, p3 = p2 + a3;
        int x = p3;
#pragma unroll
        for (int ofs = 1; ofs < 64; ofs <<= 1) {
            int t = __shfl_up(x, ofs, 64);
            if (lane >= ofs) x += t;
        }
        if (lane == 63) wsum[wid] = x;
        __syncthreads();
        if (wid == 0) {
            int y = (lane < 16) ? wsum[lane] : 0;
#pragma unroll
            for (int ofs = 1; ofs < 16; ofs <<= 1) {
                int t = __shfl_up(y, ofs, 64);
                if (lane >= ofs) y += t;
            }
            if (lane < 16) wsum[lane] = y;
        }
        __syncthreads();
        int wofs = (wid > 0) ? wsum[wid - 1] : 0;
        int carry = carry_s;
        int excl = carry + wofs + (x - p3);
        if (idx < N)     { rp[idx] = excl;          cursor[idx] = excl; }
        if (idx + 1 < N) { rp[idx + 1] = excl + a0; cursor[idx + 1] = excl + a0; }
        if (idx + 2 < N) { rp[idx + 2] = excl + p1; cursor[idx + 2] = excl + p1; }
        if (idx + 3 < N) { rp[idx + 3] = excl + p2; cursor[idx + 3] = excl + p2; }
        __syncthreads();
        if (threadIdx.x == 1023) carry_s = carry + wsum[15];
        __syncthreads();
    }
    if (threadIdx.x == 0) rp[N] = carry_s;
}

__global__ void csr_scatter(const int* __restrict__ srcI, const int* __restrict__ dstI,
                            int E, int Etot, int* __restrict__ cursor,
                            int* __restrict__ srcp) {
    int e = blockIdx.x * blockDim.x + threadIdx.x;
    if (e < Etot) {
        int s, d;
        if (e < E) { s = srcI[e]; d = dstI[e]; }
        else       { s = e - E;   d = e - E; }
        int pos = atomicAdd(&cursor[d], 1);
        srcp[pos] = s;
    }
}

// -------- single-pass fused aggregate (fp8 h gather), H=4, C=64 -------------
template<bool ELU>
__global__ __launch_bounds__(256) void gat_fused_h4(
        const unsigned* __restrict__ h8, const float* __restrict__ al_s,
        const float* __restrict__ al_d, const float* __restrict__ b,
        const int* __restrict__ rp, const int* __restrict__ srcp,
        int N, u16* __restrict__ out) {
    const int lane = threadIdx.x & 63;
    const int head = lane >> 4;
    int w = (blockIdx.x * blockDim.x + threadIdx.x) >> 6;
    int nw = (gridDim.x * blockDim.x) >> 6;
    for (int d = w; d < N; d += nw) {
        int i = rp[d], end = rp[d + 1];
        float ald = al_d[d * 4 + head];
        float acc0 = 0.f, acc1 = 0.f, acc2 = 0.f, acc3 = 0.f, L = 0.f;
        for (; i + 4 <= end; i += 4) {
            int s0 = srcp[i], s1 = srcp[i + 1], s2 = srcp[i + 2], s3 = srcp[i + 3];
            unsigned w0 = h8[(size_t)s0 * 64 + lane];
            unsigned w1 = h8[(size_t)s1 * 64 + lane];
            unsigned w2 = h8[(size_t)s2 * 64 + lane];
            unsigned w3 = h8[(size_t)s3 * 64 + lane];
            float v0 = al_s[s0 * 4 + head] + ald;
            float v1 = al_s[s1 * 4 + head] + ald;
            float v2 = al_s[s2 * 4 + head] + ald;
            float v3 = al_s[s3 * 4 + head] + ald;
            v0 = (v0 > 0.f) ? v0 : NEG_SLOPE * v0;
            v1 = (v1 > 0.f) ? v1 : NEG_SLOPE * v1;
            v2 = (v2 > 0.f) ? v2 : NEG_SLOPE * v2;
            v3 = (v3 > 0.f) ? v3 : NEG_SLOPE * v3;
            float e0 = expf(v0), e1 = expf(v1), e2 = expf(v2), e3 = expf(v3);
            L += (e0 + e1) + (e2 + e3);
            f32x2 lo, hi;
            lo = __builtin_amdgcn_cvt_pk_f32_fp8((int)w0, false);
            hi = __builtin_amdgcn_cvt_pk_f32_fp8((int)w0, true);
            acc0 = fmaf(e0, lo.x, acc0); acc1 = fmaf(e0, lo.y, acc1);
            acc2 = fmaf(e0, hi.x, acc2); acc3 = fmaf(e0, hi.y, acc3);
            lo = __builtin_amdgcn_cvt_pk_f32_fp8((int)w1, false);
            hi = __builtin_amdgcn_cvt_pk_f32_fp8((int)w1, true);
            acc0 = fmaf(e1, lo.x, acc0); acc1 = fmaf(e1, lo.y, acc1);
            acc2 = fmaf(e1, hi.x, acc2); acc3 = fmaf(e1, hi.y, acc3);
            lo = __builtin_amdgcn_cvt_pk_f32_fp8((int)w2, false);
            hi = __builtin_amdgcn_cvt_pk_f32_fp8((int)w2, true);
            acc0 = fmaf(e2, lo.x, acc0); acc1 = fmaf(e2, lo.y, acc1);
            acc2 = fmaf(e2, hi.x, acc2); acc3 = fmaf(e2, hi.y, acc3);
            lo = __builtin_amdgcn_cvt_pk_f32_fp8((int)w3, false);
            hi = __builtin_amdgcn_cvt_pk_f32_fp8((int)w3, true);
            acc0 = fmaf(e3, lo.x, acc0); acc1 = fmaf(e3, lo.y, acc1);
            acc2 = fmaf(e3, hi.x, acc2); acc3 = fmaf(e3, hi.y, acc3);
        }
        for (; i < end; ++i) {
            int s0 = srcp[i];
            unsigned w0 = h8[(size_t)s0 * 64 + lane];
            float v0 = al_s[s0 * 4 + head] + ald;
            v0 = (v0 > 0.f) ? v0 : NEG_SLOPE * v0;
            float e0 = expf(v0);
            L += e0;
            f32x2 lo = __builtin_amdgcn_cvt_pk_f32_fp8((int)w0, false);
            f32x2 hi = __builtin_amdgcn_cvt_pk_f32_fp8((int)w0, true);
            acc0 = fmaf(e0, lo.x, acc0); acc1 = fmaf(e0, lo.y, acc1);
            acc2 = fmaf(e0, hi.x, acc2); acc3 = fmaf(e0, hi.y, acc3);
        }
        float inv = 1.f / (L + 1e-16f);
        float4 bb = *reinterpret_cast<const float4*>(&b[lane * 4]);
        float o0 = fmaf(acc0, inv, bb.x);
        float o1 = fmaf(acc1, inv, bb.y);
        float o2 = fmaf(acc2, inv, bb.z);
        float o3 = fmaf(acc3, inv, bb.w);
        if (ELU) {
            o0 = (o0 > 0.f) ? o0 : expm1f(o0);
            o1 = (o1 > 0.f) ? o1 : expm1f(o1);
            o2 = (o2 > 0.f) ? o2 : expm1f(o2);
            o3 = (o3 > 0.f) ? o3 : expm1f(o3);
        }
        u16x4 ov;
        ov[0] = f2b(o0); ov[1] = f2b(o1); ov[2] = f2b(o2); ov[3] = f2b(o3);
        *reinterpret_cast<u16x4*>(&out[(size_t)d * 256 + lane * 4]) = ov;
    }
}

// ================= layer-3 linear-collapse path =============================
// al_s/al_d for layer 3; W3.a vectors recomputed per block in LDS
__global__ __launch_bounds__(256) void compute_al3(
        const u16* __restrict__ ob, const float* __restrict__ W3,
        const float* __restrict__ as3, const float* __restrict__ ad3, int N,
        float* __restrict__ al_s, float* __restrict__ al_d) {
    __shared__ float was[256], wad[256];
    {
        int t = threadIdx.x;
        float ss = 0.f, sd = 0.f;
#pragma unroll
        for (int c = 0; c < 10; ++c) {
            float w = W3[t * 10 + c];
            ss = fmaf(w, as3[c], ss);
            sd = fmaf(w, ad3[c], sd);
        }
        was[t] = ss; wad[t] = sd;
    }
    __syncthreads();
    const int lane = threadIdx.x & 63;
    int n = (blockIdx.x * blockDim.x + threadIdx.x) >> 6;
    if (n >= N) return;
    u16x4 hv = *reinterpret_cast<const u16x4*>(&ob[(size_t)n * 256 + lane * 4]);
    float4 ws = *reinterpret_cast<const float4*>(&was[lane * 4]);
    float4 wd = *reinterpret_cast<const float4*>(&wad[lane * 4]);
    float f0 = b2f((u16)hv[0]), f1 = b2f((u16)hv[1]);
    float f2 = b2f((u16)hv[2]), f3 = b2f((u16)hv[3]);
    float ss = f0 * ws.x + f1 * ws.y + f2 * ws.z + f3 * ws.w;
    float sd = f0 * wd.x + f1 * wd.y + f2 * wd.z + f3 * wd.w;
#pragma unroll
    for (int m = 1; m < 64; m <<= 1) {
        ss += __shfl_xor(ss, m, 64);
        sd += __shfl_xor(sd, m, 64);
    }
    if (lane == 0) { al_s[n] = ss; al_d[n] = sd; }
}

// wave per destination: L in-wave, then scatter exp/L to sources
__global__ __launch_bounds__(256) void l3_edge(
        const float* __restrict__ al_s, const float* __restrict__ al_d,
        const int* __restrict__ rp, const int* __restrict__ srcp,
        int N, float* __restrict__ wq) {
    const int lane = threadIdx.x & 63;
    int w = (blockIdx.x * blockDim.x + threadIdx.x) >> 6;
    int nw = (gridDim.x * blockDim.x) >> 6;
    for (int d = w; d < N; d += nw) {
        int start = rp[d], end = rp[d + 1];
        float ald = al_d[d];
        float L = 0.f;
        for (int i = start + lane; i < end; i += 64) {
            float v = al_s[srcp[i]] + ald;
            v = (v > 0.f) ? v : NEG_SLOPE * v;
            L += expf(v);
        }
#pragma unroll
        for (int m = 1; m < 64; m <<= 1) L += __shfl_xor(L, m, 64);
        float inv = 1.f / (L + 1e-16f);
        for (int i = start + lane; i < end; i += 64) {
            int s = srcp[i];
            float v = al_s[s] + ald;
            v = (v > 0.f) ? v : NEG_SLOPE * v;
            atomicAdd(&wq[s], expf(v) * inv);
        }
    }
}

// pp[256] += sum over this wave's nodes of w[n]*ob[n,:]  (atomic epilogue)
__global__ __launch_bounds__(256) void wcolsum(const u16* __restrict__ ob,
                                               const float* __restrict__ w, int N,
                                               float* __restrict__ pp) {
    const int lane = threadIdx.x & 63;
    int wv = (blockIdx.x * blockDim.x + threadIdx.x) >> 6;
    int nw = (gridDim.x * blockDim.x) >> 6;
    float a0 = 0.f, a1 = 0.f, a2 = 0.f, a3 = 0.f;
    for (int n = wv; n < N; n += nw) {
        float wn = w[n];
        u16x4 hv = *reinterpret_cast<const u16x4*>(&ob[(size_t)n * 256 + lane * 4]);
        a0 = fmaf(wn, b2f((u16)hv[0]), a0);
        a1 = fmaf(wn, b2f((u16)hv[1]), a1);
        a2 = fmaf(wn, b2f((u16)hv[2]), a2);
        a3 = fmaf(wn, b2f((u16)hv[3]), a3);
    }
    atomicAdd(&pp[lane * 4 + 0], a0);
    atomicAdd(&pp[lane * 4 + 1], a1);
    atomicAdd(&pp[lane * 4 + 2], a2);
    atomicAdd(&pp[lane * 4 + 3], a3);
}

// out = log_softmax(pp/N @ W3 + b3)
__global__ void final_out(const float* __restrict__ pp, const float* __restrict__ W3,
                          const float* __restrict__ b3, int N, float* __restrict__ out) {
    __shared__ float acc[10];
    int t = threadIdx.x;  // 256
    if (t < 10) acc[t] = 0.f;
    __syncthreads();
    float pk = pp[t] / (float)N;
#pragma unroll
    for (int c = 0; c < 10; ++c) atomicAdd(&acc[c], pk * W3[t * 10 + c]);
    __syncthreads();
    if (t == 0) {
        float p[10];
        float mx = -INFINITY;
        for (int c = 0; c < 10; ++c) {
            p[c] = acc[c] + b3[c];
            mx = fmaxf(mx, p[c]);
        }
        float s = 0.f;
        for (int c = 0; c < 10; ++c) s += expf(p[c] - mx);
        float ls = logf(s);
        for (int c = 0; c < 10; ++c) out[c] = p[c] - mx - ls;
    }
}

extern "C" void kernel_launch(void* const* d_in, const int* in_sizes, int n_in,
                              void* d_out, int out_size, void* d_ws, size_t ws_size,
                              hipStream_t stream) {
    const float* x   = (const float*)d_in[0];
    const int*   ei  = (const int*)d_in[1];
    const float* W1  = (const float*)d_in[2];
    const float* as1 = (const float*)d_in[3];
    const float* ad1 = (const float*)d_in[4];
    const float* b1  = (const float*)d_in[5];
    const float* W2  = (const float*)d_in[6];
    const float* as2 = (const float*)d_in[7];
    const float* ad2 = (const float*)d_in[8];
    const float* b2  = (const float*)d_in[9];
    const float* W3  = (const float*)d_in[10];
    const float* as3 = (const float*)d_in[11];
    const float* ad3 = (const float*)d_in[12];
    const float* b3  = (const float*)d_in[13];
    float* out = (float*)d_out;

    const int N = in_sizes[0] / 128;   // 50000
    const int E = in_sizes[1] / 2;     // 800000
    const int Etot = E + N;
    const int* srcI = ei;
    const int* dstI = ei + E;

    char* base = (char*)d_ws;
    size_t off = 0;
    auto alloc = [&](size_t bytes) {
        void* p = base + off;
        off = (off + bytes + 255) & ~(size_t)255;
        return p;
    };
    u16* x_bf  = (u16*)alloc((size_t)N * 128 * 2);
    u16* h_bf  = (u16*)alloc((size_t)N * 256 * 2);
    unsigned* h8 = (unsigned*)alloc((size_t)N * 256);
    u16* oa_bf = (u16*)alloc((size_t)N * 256 * 2);
    u16* ob_bf = (u16*)alloc((size_t)N * 256 * 2);
    u16* w1t   = (u16*)alloc(256 * 128 * 2);
    u16* w2t   = (u16*)alloc(256 * 256 * 2);
    float* al_s = (float*)alloc((size_t)N * 4 * 4);
    float* al_d = (float*)alloc((size_t)N * 4 * 4);
    // contiguous zero region: cnt | Lwq | pp
    int* cnt    = (int*)alloc((size_t)N * 4);
    float* wq   = (float*)alloc((size_t)N * 4);
    float* pp   = (float*)alloc(256 * 4);
    int nzero = N + N + 256;           // cnt, wq, pp are contiguous (256B-aligned each;
    // alloc pads to 256B => still contiguous as one range from cnt start)
    int* rp     = (int*)alloc((size_t)(N + 1) * 4);
    int* cursor = (int*)alloc((size_t)N * 4);
    int* srcp   = (int*)alloc((size_t)Etot * 4);

    // ---- prep: cast x, transpose weights, zero scratch (one dispatch) ----
    const int n4 = N * 128 / 4;
    const int B0 = (n4 + 255) / 256;
    const int B1 = B0 + (128 * 256 + 255) / 256;
    const int B2 = B1 + (256 * 256 + 255) / 256;
    // zero range covers cnt..pp; compute span from pointers to be safe
    int span = (int)(((char*)(pp + 256) - (char*)cnt) / 4);
    const int B3 = B2 + (span + 255) / 256;
    prep<<<B3, 256, 0, stream>>>(x, x_bf, n4, W1, w1t, W2, w2t,
                                 cnt, span, B0, B1, B2);

    deg_hist<<<(Etot + 255) / 256, 256, 0, stream>>>(dstI, E, Etot, cnt);
    scan_excl4<<<1, 1024, 0, stream>>>(cnt, rp, cursor, N);
    csr_scatter<<<(Etot + 255) / 256, 256, 0, stream>>>(srcI, dstI, E, Etot, cursor, srcp);

    const int FUSED_BLOCKS = (N + 3) / 4;
    const int GX = (N + 127) / 128;

    // ---- layer 1: x_bf[N,128] -> oa_bf[N,256], ELU ----
    {
        dim3 g(GX, 2);
        gemm_mfma<<<g, 256, 0, stream>>>(x_bf, w1t, h_bf, N, 128, 256);
        compute_al_cast<<<(N * 4 + 255) / 256, 256, 0, stream>>>(h_bf, as1, ad1, N,
                                                                 al_s, al_d, h8);
        gat_fused_h4<true><<<FUSED_BLOCKS, 256, 0, stream>>>(
            h8, al_s, al_d, b1, rp, srcp, N, oa_bf);
    }
    // ---- layer 2: oa_bf -> ob_bf, ELU ----
    {
        dim3 g(GX, 2);
        gemm_mfma<<<g, 256, 0, stream>>>(oa_bf, w2t, h_bf, N, 256, 256);
        compute_al_cast<<<(N * 4 + 255) / 256, 256, 0, stream>>>(h_bf, as2, ad2, N,
                                                                 al_s, al_d, h8);
        gat_fused_h4<true><<<FUSED_BLOCKS, 256, 0, stream>>>(
            h8, al_s, al_d, b2, rp, srcp, N, ob_bf);
    }
    // ---- layer 3 (linear-collapsed): pooled = (1/N * sum_s w_s ob_s) @ W3 + b3
    {
        compute_al3<<<(N + 3) / 4, 256, 0, stream>>>(ob_bf, W3, as3, ad3, N, al_s, al_d);
        l3_edge<<<(N + 3) / 4, 256, 0, stream>>>(al_s, al_d, rp, srcp, N, wq);
        wcolsum<<<128, 256, 0, stream>>>(ob_bf, wq, N, pp);
        final_out<<<1, 256, 0, stream>>>(pp, W3, b3, N, out);
    }
}

// Round 8
// 444.433 us; speedup vs baseline: 1.4478x; 1.0980x over previous
//
#include <hip/hip_runtime.h>
#include <math.h>

#define NEG_SLOPE 0.2f

typedef __attribute__((ext_vector_type(8))) short bf16x8;
typedef __attribute__((ext_vector_type(4))) float f32x4;
typedef __attribute__((ext_vector_type(2))) float f32x2;
typedef unsigned short u16;
typedef __attribute__((ext_vector_type(4))) unsigned short u16x4;

__device__ __forceinline__ float b2f(u16 u) {
    return __uint_as_float(((unsigned)u) << 16);
}
__device__ __forceinline__ u16 f2b(float f) {
    unsigned u = __float_as_uint(f);
    unsigned r = (u + 0x7fffu + ((u >> 16) & 1u)) >> 16;
    return (u16)r;
}

// ---------------- fused prep: cast x, transpose W1/W2, zero scratch --------
__global__ void prep(const float* __restrict__ x, u16* __restrict__ x_bf, int n4,
                     const float* __restrict__ W1, u16* __restrict__ w1t,
                     const float* __restrict__ W2, u16* __restrict__ w2t,
                     int* __restrict__ zero_base, int nzero,
                     int B0, int B1, int B2) {
    int blk = blockIdx.x;
    if (blk < B0) {
        int i = blk * 256 + threadIdx.x;
        if (i < n4) {
            float4 v = *reinterpret_cast<const float4*>(&x[i * 4]);
            u16x4 o;
            o[0] = f2b(v.x); o[1] = f2b(v.y); o[2] = f2b(v.z); o[3] = f2b(v.w);
            *reinterpret_cast<u16x4*>(&x_bf[i * 4]) = o;
        }
    } else if (blk < B1) {
        int i = (blk - B0) * 256 + threadIdx.x;  // [M][K], K=128, M=256
        if (i < 128 * 256) {
            int m = i >> 7, k = i & 127;
            w1t[i] = f2b(W1[(size_t)k * 256 + m]);
        }
    } else if (blk < B2) {
        int i = (blk - B1) * 256 + threadIdx.x;  // K=256, M=256
        if (i < 256 * 256) {
            int m = i >> 8, k = i & 255;
            w2t[i] = f2b(W2[(size_t)k * 256 + m]);
        }
    } else {
        int i = (blk - B2) * 256 + threadIdx.x;
        if (i < nzero) zero_base[i] = 0;
    }
}

// ---------------- MFMA GEMM: C[N,M] bf16 = A[N,K] bf16 * Bt[M,K]^T ----------
__global__ __launch_bounds__(256) void gemm_mfma(
        const u16* __restrict__ A, const u16* __restrict__ Bt,
        u16* __restrict__ C, int N, int K, int M) {
    __shared__ u16 As[128 * 64];
    __shared__ u16 Bs[128 * 64];
    const int tid = threadIdx.x;
    const int lane = tid & 63;
    const int wid = tid >> 6;
    const int wr = wid >> 1, wc = wid & 1;
    const int row0 = blockIdx.x * 128;
    const int col0 = blockIdx.y * 128;
    f32x4 acc[4][4] = {};
    for (int k0 = 0; k0 < K; k0 += 64) {
        if (k0) __syncthreads();
#pragma unroll
        for (int i = 0; i < 4; ++i) {
            int chunk = i * 256 + tid;
            int row = chunk >> 3;
            int slot = chunk & 7;
            int grow = row0 + row; if (grow >= N) grow = N - 1;
            bf16x8 v = *reinterpret_cast<const bf16x8*>(&A[(size_t)grow * K + k0 + slot * 8]);
            int swz = (chunk & ~7) | (slot ^ (row & 7));
            *reinterpret_cast<bf16x8*>(&As[swz * 8]) = v;
        }
#pragma unroll
        for (int i = 0; i < 4; ++i) {
            int chunk = i * 256 + tid;
            int row = chunk >> 3;
            int slot = chunk & 7;
            int gcol = col0 + row;
            bf16x8 v = *reinterpret_cast<const bf16x8*>(&Bt[(size_t)gcol * K + k0 + slot * 8]);
            int swz = (chunk & ~7) | (slot ^ (row & 7));
            *reinterpret_cast<bf16x8*>(&Bs[swz * 8]) = v;
        }
        __syncthreads();
#pragma unroll
        for (int kk = 0; kk < 2; ++kk) {
            bf16x8 ax[4], bx[4];
#pragma unroll
            for (int m = 0; m < 4; ++m) {
                int row = wr * 64 + m * 16 + (lane & 15);
                int slot = kk * 4 + (lane >> 4);
                ax[m] = *reinterpret_cast<const bf16x8*>(&As[(row * 8 + (slot ^ (row & 7))) * 8]);
            }
#pragma unroll
            for (int n = 0; n < 4; ++n) {
                int row = wc * 64 + n * 16 + (lane & 15);
                int slot = kk * 4 + (lane >> 4);
                bx[n] = *reinterpret_cast<const bf16x8*>(&Bs[(row * 8 + (slot ^ (row & 7))) * 8]);
            }
#pragma unroll
            for (int m = 0; m < 4; ++m)
#pragma unroll
                for (int n = 0; n < 4; ++n)
                    acc[m][n] = __builtin_amdgcn_mfma_f32_16x16x32_bf16(
                        ax[m], bx[n], acc[m][n], 0, 0, 0);
        }
    }
    const int crow = row0 + wr * 64;
    const int ccol = col0 + wc * 64;
#pragma unroll
    for (int m = 0; m < 4; ++m)
#pragma unroll
        for (int n = 0; n < 4; ++n)
#pragma unroll
            for (int r = 0; r < 4; ++r) {
                int rg = crow + m * 16 + (lane >> 4) * 4 + r;
                int cg = ccol + n * 16 + (lane & 15);
                if (rg < N) C[(size_t)rg * M + cg] = f2b(acc[m][n][r]);
            }
}

// ------- per-node attention dots + fp8 re-encode of h (H=4, C=64) ----------
__global__ void compute_al_cast(const u16* __restrict__ h, const float* __restrict__ a_s,
                                const float* __restrict__ a_d, int N,
                                float* __restrict__ al_s, float* __restrict__ al_d,
                                unsigned* __restrict__ h8) {
    int i = blockIdx.x * blockDim.x + threadIdx.x;   // n*4 + head
    if (i < N * 4) {
        int hh = i & 3;
        const u16* hp = h + (size_t)(i >> 2) * 256 + hh * 64;
        const float* as = a_s + hh * 64;
        const float* ad = a_d + hh * 64;
        unsigned* op = h8 + (size_t)(i >> 2) * 64 + hh * 16;
        float ss = 0.f, sd = 0.f;
#pragma unroll
        for (int c0 = 0; c0 < 64; c0 += 8) {
            bf16x8 v = *reinterpret_cast<const bf16x8*>(&hp[c0]);
            float f[8];
#pragma unroll
            for (int j = 0; j < 8; ++j) {
                f[j] = b2f((u16)v[j]);
                ss = fmaf(f[j], as[c0 + j], ss);
                sd = fmaf(f[j], ad[c0 + j], sd);
            }
            int w0 = 0, w1 = 0;
            w0 = __builtin_amdgcn_cvt_pk_fp8_f32(f[0], f[1], w0, false);
            w0 = __builtin_amdgcn_cvt_pk_fp8_f32(f[2], f[3], w0, true);
            w1 = __builtin_amdgcn_cvt_pk_fp8_f32(f[4], f[5], w1, false);
            w1 = __builtin_amdgcn_cvt_pk_fp8_f32(f[6], f[7], w1, true);
            op[c0 / 4]     = (unsigned)w0;
            op[c0 / 4 + 1] = (unsigned)w1;
        }
        al_s[i] = ss; al_d[i] = sd;
    }
}

// ---------------- CSR build ----------------
__global__ void deg_hist(const int* __restrict__ dstI, int E, int Etot,
                         int* __restrict__ cnt) {
    int e = blockIdx.x * blockDim.x + threadIdx.x;
    if (e < Etot) {
        int d = (e < E) ? dstI[e] : (e - E);
        atomicAdd(&cnt[d], 1);
    }
}

// single-block exclusive scan, 4 elements/thread (writes rp AND cursor)
__global__ __launch_bounds__(1024) void scan_excl4(const int* __restrict__ cnt,
                                                   int* __restrict__ rp,
                                                   int* __restrict__ cursor, int N) {
    __shared__ int wsum[16];
    __shared__ int carry_s;
    int lane = threadIdx.x & 63;
    int wid = threadIdx.x >> 6;
    if (threadIdx.x == 0) carry_s = 0;
    __syncthreads();
    for (int base = 0; base < N; base += 4096) {
        int idx = base + (int)threadIdx.x * 4;
        int a0 = 0, a1 = 0, a2 = 0, a3 = 0;
        if (idx + 3 < N) {
            int4 v = *reinterpret_cast<const int4*>(&cnt[idx]);
            a0 = v.x; a1 = v.y; a2 = v.z; a3 = v.w;
        } else {
            if (idx < N)     a0 = cnt[idx];
            if (idx + 1 < N) a1 = cnt[idx + 1];
            if (idx + 2 < N) a2 = cnt[idx + 2];
        }
        int p1 = a0 + a1, p2 = p1 + a2, p3 = p2 + a3;
        int x = p3;
#pragma unroll
        for (int ofs = 1; ofs < 64; ofs <<= 1) {
            int t = __shfl_up(x, ofs, 64);
            if (lane >= ofs) x += t;
        }
        if (lane == 63) wsum[wid] = x;
        __syncthreads();
        if (wid == 0) {
            int y = (lane < 16) ? wsum[lane] : 0;
#pragma unroll
            for (int ofs = 1; ofs < 16; ofs <<= 1) {
                int t = __shfl_up(y, ofs, 64);
                if (lane >= ofs) y += t;
            }
            if (lane < 16) wsum[lane] = y;
        }
        __syncthreads();
        int wofs = (wid > 0) ? wsum[wid - 1] : 0;
        int carry = carry_s;
        int excl = carry + wofs + (x - p3);
        if (idx < N)     { rp[idx] = excl;          cursor[idx] = excl; }
        if (idx + 1 < N) { rp[idx + 1] = excl + a0; cursor[idx + 1] = excl + a0; }
        if (idx + 2 < N) { rp[idx + 2] = excl + p1; cursor[idx + 2] = excl + p1; }
        if (idx + 3 < N) { rp[idx + 3] = excl + p2; cursor[idx + 3] = excl + p2; }
        __syncthreads();
        if (threadIdx.x == 1023) carry_s = carry + wsum[15];
        __syncthreads();
    }
    if (threadIdx.x == 0) rp[N] = carry_s;
}

__global__ void csr_scatter(const int* __restrict__ srcI, const int* __restrict__ dstI,
                            int E, int Etot, int* __restrict__ cursor,
                            int* __restrict__ srcp) {
    int e = blockIdx.x * blockDim.x + threadIdx.x;
    if (e < Etot) {
        int s, d;
        if (e < E) { s = srcI[e]; d = dstI[e]; }
        else       { s = e - E;   d = e - E; }
        int pos = atomicAdd(&cursor[d], 1);
        srcp[pos] = s;
    }
}

// -------- single-pass fused aggregate (fp8 h gather), H=4, C=64 -------------
template<bool ELU>
__global__ __launch_bounds__(256) void gat_fused_h4(
        const unsigned* __restrict__ h8, const float* __restrict__ al_s,
        const float* __restrict__ al_d, const float* __restrict__ b,
        const int* __restrict__ rp, const int* __restrict__ srcp,
        int N, u16* __restrict__ out) {
    const int lane = threadIdx.x & 63;
    const int head = lane >> 4;
    int w = (blockIdx.x * blockDim.x + threadIdx.x) >> 6;
    int nw = (gridDim.x * blockDim.x) >> 6;
    for (int d = w; d < N; d += nw) {
        int i = rp[d], end = rp[d + 1];
        float ald = al_d[d * 4 + head];
        float acc0 = 0.f, acc1 = 0.f, acc2 = 0.f, acc3 = 0.f, L = 0.f;
        for (; i + 4 <= end; i += 4) {
            int s0 = srcp[i], s1 = srcp[i + 1], s2 = srcp[i + 2], s3 = srcp[i + 3];
            unsigned w0 = h8[(size_t)s0 * 64 + lane];
            unsigned w1 = h8[(size_t)s1 * 64 + lane];
            unsigned w2 = h8[(size_t)s2 * 64 + lane];
            unsigned w3 = h8[(size_t)s3 * 64 + lane];
            float v0 = al_s[s0 * 4 + head] + ald;
            float v1 = al_s[s1 * 4 + head] + ald;
            float v2 = al_s[s2 * 4 + head] + ald;
            float v3 = al_s[s3 * 4 + head] + ald;
            v0 = (v0 > 0.f) ? v0 : NEG_SLOPE * v0;
            v1 = (v1 > 0.f) ? v1 : NEG_SLOPE * v1;
            v2 = (v2 > 0.f) ? v2 : NEG_SLOPE * v2;
            v3 = (v3 > 0.f) ? v3 : NEG_SLOPE * v3;
            float e0 = expf(v0), e1 = expf(v1), e2 = expf(v2), e3 = expf(v3);
            L += (e0 + e1) + (e2 + e3);
            f32x2 lo, hi;
            lo = __builtin_amdgcn_cvt_pk_f32_fp8((int)w0, false);
            hi = __builtin_amdgcn_cvt_pk_f32_fp8((int)w0, true);
            acc0 = fmaf(e0, lo.x, acc0); acc1 = fmaf(e0, lo.y, acc1);
            acc2 = fmaf(e0, hi.x, acc2); acc3 = fmaf(e0, hi.y, acc3);
            lo = __builtin_amdgcn_cvt_pk_f32_fp8((int)w1, false);
            hi = __builtin_amdgcn_cvt_pk_f32_fp8((int)w1, true);
            acc0 = fmaf(e1, lo.x, acc0); acc1 = fmaf(e1, lo.y, acc1);
            acc2 = fmaf(e1, hi.x, acc2); acc3 = fmaf(e1, hi.y, acc3);
            lo = __builtin_amdgcn_cvt_pk_f32_fp8((int)w2, false);
            hi = __builtin_amdgcn_cvt_pk_f32_fp8((int)w2, true);
            acc0 = fmaf(e2, lo.x, acc0); acc1 = fmaf(e2, lo.y, acc1);
            acc2 = fmaf(e2, hi.x, acc2); acc3 = fmaf(e2, hi.y, acc3);
            lo = __builtin_amdgcn_cvt_pk_f32_fp8((int)w3, false);
            hi = __builtin_amdgcn_cvt_pk_f32_fp8((int)w3, true);
            acc0 = fmaf(e3, lo.x, acc0); acc1 = fmaf(e3, lo.y, acc1);
            acc2 = fmaf(e3, hi.x, acc2); acc3 = fmaf(e3, hi.y, acc3);
        }
        for (; i < end; ++i) {
            int s0 = srcp[i];
            unsigned w0 = h8[(size_t)s0 * 64 + lane];
            float v0 = al_s[s0 * 4 + head] + ald;
            v0 = (v0 > 0.f) ? v0 : NEG_SLOPE * v0;
            float e0 = expf(v0);
            L += e0;
            f32x2 lo = __builtin_amdgcn_cvt_pk_f32_fp8((int)w0, false);
            f32x2 hi = __builtin_amdgcn_cvt_pk_f32_fp8((int)w0, true);
            acc0 = fmaf(e0, lo.x, acc0); acc1 = fmaf(e0, lo.y, acc1);
            acc2 = fmaf(e0, hi.x, acc2); acc3 = fmaf(e0, hi.y, acc3);
        }
        float inv = 1.f / (L + 1e-16f);
        float4 bb = *reinterpret_cast<const float4*>(&b[lane * 4]);
        float o0 = fmaf(acc0, inv, bb.x);
        float o1 = fmaf(acc1, inv, bb.y);
        float o2 = fmaf(acc2, inv, bb.z);
        float o3 = fmaf(acc3, inv, bb.w);
        if (ELU) {
            o0 = (o0 > 0.f) ? o0 : expm1f(o0);
            o1 = (o1 > 0.f) ? o1 : expm1f(o1);
            o2 = (o2 > 0.f) ? o2 : expm1f(o2);
            o3 = (o3 > 0.f) ? o3 : expm1f(o3);
        }
        u16x4 ov;
        ov[0] = f2b(o0); ov[1] = f2b(o1); ov[2] = f2b(o2); ov[3] = f2b(o3);
        *reinterpret_cast<u16x4*>(&out[(size_t)d * 256 + lane * 4]) = ov;
    }
}

// ================= layer-3 linear-collapse path =============================
__global__ __launch_bounds__(256) void compute_al3(
        const u16* __restrict__ ob, const float* __restrict__ W3,
        const float* __restrict__ as3, const float* __restrict__ ad3, int N,
        float* __restrict__ al_s, float* __restrict__ al_d) {
    __shared__ float was[256], wad[256];
    {
        int t = threadIdx.x;
        float ss = 0.f, sd = 0.f;
#pragma unroll
        for (int c = 0; c < 10; ++c) {
            float w = W3[t * 10 + c];
            ss = fmaf(w, as3[c], ss);
            sd = fmaf(w, ad3[c], sd);
        }
        was[t] = ss; wad[t] = sd;
    }
    __syncthreads();
    const int lane = threadIdx.x & 63;
    int n = (blockIdx.x * blockDim.x + threadIdx.x) >> 6;
    if (n >= N) return;
    u16x4 hv = *reinterpret_cast<const u16x4*>(&ob[(size_t)n * 256 + lane * 4]);
    float4 ws = *reinterpret_cast<const float4*>(&was[lane * 4]);
    float4 wd = *reinterpret_cast<const float4*>(&wad[lane * 4]);
    float f0 = b2f((u16)hv[0]), f1 = b2f((u16)hv[1]);
    float f2 = b2f((u16)hv[2]), f3 = b2f((u16)hv[3]);
    float ss = f0 * ws.x + f1 * ws.y + f2 * ws.z + f3 * ws.w;
    float sd = f0 * wd.x + f1 * wd.y + f2 * wd.z + f3 * wd.w;
#pragma unroll
    for (int m = 1; m < 64; m <<= 1) {
        ss += __shfl_xor(ss, m, 64);
        sd += __shfl_xor(sd, m, 64);
    }
    if (lane == 0) { al_s[n] = ss; al_d[n] = sd; }
}

// wave per destination: L in-wave, then scatter exp/L to sources
__global__ __launch_bounds__(256) void l3_edge(
        const float* __restrict__ al_s, const float* __restrict__ al_d,
        const int* __restrict__ rp, const int* __restrict__ srcp,
        int N, float* __restrict__ wq) {
    const int lane = threadIdx.x & 63;
    int w = (blockIdx.x * blockDim.x + threadIdx.x) >> 6;
    int nw = (gridDim.x * blockDim.x) >> 6;
    for (int d = w; d < N; d += nw) {
        int start = rp[d], end = rp[d + 1];
        float ald = al_d[d];
        float L = 0.f;
        for (int i = start + lane; i < end; i += 64) {
            float v = al_s[srcp[i]] + ald;
            v = (v > 0.f) ? v : NEG_SLOPE * v;
            L += expf(v);
        }
#pragma unroll
        for (int m = 1; m < 64; m <<= 1) L += __shfl_xor(L, m, 64);
        float inv = 1.f / (L + 1e-16f);
        for (int i = start + lane; i < end; i += 64) {
            int s = srcp[i];
            float v = al_s[s] + ald;
            v = (v > 0.f) ? v : NEG_SLOPE * v;
            atomicAdd(&wq[s], expf(v) * inv);
        }
    }
}

// pp[256] += w-weighted column sum of ob; LDS-reduced per block, then atomics
__global__ __launch_bounds__(256) void wcolsum(const u16* __restrict__ ob,
                                               const float* __restrict__ w, int N,
                                               float* __restrict__ pp) {
    __shared__ float sh[4][256];
    const int lane = threadIdx.x & 63;
    const int wid = threadIdx.x >> 6;
    int wv = (blockIdx.x * blockDim.x + threadIdx.x) >> 6;
    int nw = (gridDim.x * blockDim.x) >> 6;
    float a0 = 0.f, a1 = 0.f, a2 = 0.f, a3 = 0.f;
    for (int n = wv; n < N; n += nw) {
        float wn = w[n];
        u16x4 hv = *reinterpret_cast<const u16x4*>(&ob[(size_t)n * 256 + lane * 4]);
        a0 = fmaf(wn, b2f((u16)hv[0]), a0);
        a1 = fmaf(wn, b2f((u16)hv[1]), a1);
        a2 = fmaf(wn, b2f((u16)hv[2]), a2);
        a3 = fmaf(wn, b2f((u16)hv[3]), a3);
    }
    sh[wid][lane * 4 + 0] = a0;
    sh[wid][lane * 4 + 1] = a1;
    sh[wid][lane * 4 + 2] = a2;
    sh[wid][lane * 4 + 3] = a3;
    __syncthreads();
    int t = threadIdx.x;
    float s = sh[0][t] + sh[1][t] + sh[2][t] + sh[3][t];
    atomicAdd(&pp[t], s);
}

// out = log_softmax(pp/N @ W3 + b3)
__global__ void final_out(const float* __restrict__ pp, const float* __restrict__ W3,
                          const float* __restrict__ b3, int N, float* __restrict__ out) {
    __shared__ float acc[10];
    int t = threadIdx.x;  // 256
    if (t < 10) acc[t] = 0.f;
    __syncthreads();
    float pk = pp[t] / (float)N;
#pragma unroll
    for (int c = 0; c < 10; ++c) atomicAdd(&acc[c], pk * W3[t * 10 + c]);
    __syncthreads();
    if (t == 0) {
        float p[10];
        float mx = -INFINITY;
        for (int c = 0; c < 10; ++c) {
            p[c] = acc[c] + b3[c];
            mx = fmaxf(mx, p[c]);
        }
        float s = 0.f;
        for (int c = 0; c < 10; ++c) s += expf(p[c] - mx);
        float ls = logf(s);
        for (int c = 0; c < 10; ++c) out[c] = p[c] - mx - ls;
    }
}

extern "C" void kernel_launch(void* const* d_in, const int* in_sizes, int n_in,
                              void* d_out, int out_size, void* d_ws, size_t ws_size,
                              hipStream_t stream) {
    const float* x   = (const float*)d_in[0];
    const int*   ei  = (const int*)d_in[1];
    const float* W1  = (const float*)d_in[2];
    const float* as1 = (const float*)d_in[3];
    const float* ad1 = (const float*)d_in[4];
    const float* b1  = (const float*)d_in[5];
    const float* W2  = (const float*)d_in[6];
    const float* as2 = (const float*)d_in[7];
    const float* ad2 = (const float*)d_in[8];
    const float* b2  = (const float*)d_in[9];
    const float* W3  = (const float*)d_in[10];
    const float* as3 = (const float*)d_in[11];
    const float* ad3 = (const float*)d_in[12];
    const float* b3  = (const float*)d_in[13];
    float* out = (float*)d_out;

    const int N = in_sizes[0] / 128;   // 50000
    const int E = in_sizes[1] / 2;     // 800000
    const int Etot = E + N;
    const int* srcI = ei;
    const int* dstI = ei + E;

    char* base = (char*)d_ws;
    size_t off = 0;
    auto alloc = [&](size_t bytes) {
        void* p = base + off;
        off = (off + bytes + 255) & ~(size_t)255;
        return p;
    };
    u16* x_bf  = (u16*)alloc((size_t)N * 128 * 2);
    u16* h_bf  = (u16*)alloc((size_t)N * 256 * 2);
    unsigned* h8 = (unsigned*)alloc((size_t)N * 256);
    u16* oa_bf = (u16*)alloc((size_t)N * 256 * 2);
    u16* ob_bf = (u16*)alloc((size_t)N * 256 * 2);
    u16* w1t   = (u16*)alloc(256 * 128 * 2);
    u16* w2t   = (u16*)alloc(256 * 256 * 2);
    float* al_s = (float*)alloc((size_t)N * 4 * 4);
    float* al_d = (float*)alloc((size_t)N * 4 * 4);
    // contiguous zero region: cnt | wq | pp
    int* cnt    = (int*)alloc((size_t)N * 4);
    float* wq   = (float*)alloc((size_t)N * 4);
    float* pp   = (float*)alloc(256 * 4);
    int* rp     = (int*)alloc((size_t)(N + 1) * 4);
    int* cursor = (int*)alloc((size_t)N * 4);
    int* srcp   = (int*)alloc((size_t)Etot * 4);

    // ---- prep: cast x, transpose weights, zero scratch (one dispatch) ----
    const int n4 = N * 128 / 4;
    const int B0 = (n4 + 255) / 256;
    const int B1 = B0 + (128 * 256 + 255) / 256;
    const int B2 = B1 + (256 * 256 + 255) / 256;
    int span = (int)(((char*)(pp + 256) - (char*)cnt) / 4);
    const int B3 = B2 + (span + 255) / 256;
    prep<<<B3, 256, 0, stream>>>(x, x_bf, n4, W1, w1t, W2, w2t,
                                 cnt, span, B0, B1, B2);

    deg_hist<<<(Etot + 255) / 256, 256, 0, stream>>>(dstI, E, Etot, cnt);
    scan_excl4<<<1, 1024, 0, stream>>>(cnt, rp, cursor, N);
    csr_scatter<<<(Etot + 255) / 256, 256, 0, stream>>>(srcI, dstI, E, Etot, cursor, srcp);

    const int FUSED_BLOCKS = (N + 3) / 4;
    const int GX = (N + 127) / 128;

    // ---- layer 1: x_bf[N,128] -> oa_bf[N,256], ELU ----
    {
        dim3 g(GX, 2);
        gemm_mfma<<<g, 256, 0, stream>>>(x_bf, w1t, h_bf, N, 128, 256);
        compute_al_cast<<<(N * 4 + 255) / 256, 256, 0, stream>>>(h_bf, as1, ad1, N,
                                                                 al_s, al_d, h8);
        gat_fused_h4<true><<<FUSED_BLOCKS, 256, 0, stream>>>(
            h8, al_s, al_d, b1, rp, srcp, N, oa_bf);
    }
    // ---- layer 2: oa_bf -> ob_bf, ELU ----
    {
        dim3 g(GX, 2);
        gemm_mfma<<<g, 256, 0, stream>>>(oa_bf, w2t, h_bf, N, 256, 256);
        compute_al_cast<<<(N * 4 + 255) / 256, 256, 0, stream>>>(h_bf, as2, ad2, N,
                                                                 al_s, al_d, h8);
        gat_fused_h4<true><<<FUSED_BLOCKS, 256, 0, stream>>>(
            h8, al_s, al_d, b2, rp, srcp, N, ob_bf);
    }
    // ---- layer 3 (linear-collapsed): pooled = (1/N * sum_s w_s ob_s) @ W3 + b3
    {
        compute_al3<<<(N + 3) / 4, 256, 0, stream>>>(ob_bf, W3, as3, ad3, N, al_s, al_d);
        l3_edge<<<(N + 3) / 4, 256, 0, stream>>>(al_s, al_d, rp, srcp, N, wq);
        wcolsum<<<1024, 256, 0, stream>>>(ob_bf, wq, N, pp);
        final_out<<<1, 256, 0, stream>>>(pp, W3, b3, N, out);
    }
}